// Round 7
// baseline (1109.180 us; speedup 1.0000x reference)
//
#include <hip/hip_runtime.h>
#include <math.h>

#define N_TOK 8192
#define DIM   768
#define MEMN  10000
#define MEMP  10240            // padded to 40*256
#define TQ    64
#define TM    256
#define NSPLIT 2
#define TILES_PER_SPLIT 20

constexpr float SCALE = 0.036084391824351615f;  // 1/sqrt(768)

typedef short bf16x8 __attribute__((ext_vector_type(8)));
typedef float f32x4  __attribute__((ext_vector_type(4)));

__device__ __forceinline__ unsigned short f2bf(float f) {
    unsigned u = __float_as_uint(f);
    unsigned r = (u + 0x7fffu + ((u >> 16) & 1u)) >> 16;   // RTN-even
    return (unsigned short)r;
}

// ---------------------------------------------------------------------------
// memF: fragment-linear bf16 layout of mem for phase 1 (QK^T B-operand).
// slot(mb, kc, l16, quad, j) = mem[mb*16 + l16][kc*32 + quad*8 + j]
// offset (ushorts) = (mb*24 + kc)*512 + (l16*4 + quad)*8
// ---------------------------------------------------------------------------
__global__ void cvt_memF(const float* __restrict__ mem, unsigned short* __restrict__ dst)
{
    const int mb = blockIdx.x;                       // 0..639
    const bool zero = (mb >= MEMN / 16);             // 625 exact blocks valid
#pragma unroll
    for (int it = 0; it < 6; ++it) {
        const int s   = it * 256 + threadIdx.x;      // 0..1535
        const int kc  = s >> 6;
        const int r   = s & 63;
        const int l16 = r >> 2, q = r & 3;
        unsigned short o[8];
        if (!zero) {
            const float* src = &mem[(size_t)(mb * 16 + l16) * DIM + kc * 32 + q * 8];
            float4 v0 = *(const float4*)src;
            float4 v1 = *(const float4*)(src + 4);
            o[0] = f2bf(v0.x); o[1] = f2bf(v0.y); o[2] = f2bf(v0.z); o[3] = f2bf(v0.w);
            o[4] = f2bf(v1.x); o[5] = f2bf(v1.y); o[6] = f2bf(v1.z); o[7] = f2bf(v1.w);
        } else {
#pragma unroll
            for (int j = 0; j < 8; ++j) o[j] = 0;
        }
        *(uint4*)&dst[((size_t)mb * 24 + kc) * 512 + r * 8] = *(const uint4*)o;
    }
}

// ---------------------------------------------------------------------------
// Q fp32 -> bf16 (row-major, same layout)
// ---------------------------------------------------------------------------
__global__ void cvt_qH(const float* __restrict__ q, unsigned short* __restrict__ dst)
{
    const size_t i = ((size_t)blockIdx.x * 256 + threadIdx.x) * 4;
    float4 v = *(const float4*)&q[i];
    ushort4 o;
    o.x = f2bf(v.x); o.y = f2bf(v.y); o.z = f2bf(v.z); o.w = f2bf(v.w);
    *(ushort4*)&dst[i] = o;
}

// ---------------------------------------------------------------------------
// memS: fragment-linear transposed layout for phase 2 (PV B-operand).
// slot(db, mc, l16, quad, j) = mem[mc*32 + quad*8 + j][db*16 + l16]  (0 if m>=10000)
// offset (ushorts) = (db*320 + mc)*512 + (l16*4 + quad)*8
// ---------------------------------------------------------------------------
__global__ void cvt_memS(const float* __restrict__ mem, unsigned short* __restrict__ dst)
{
    __shared__ float T[32][65];
    const int mc = blockIdx.x;              // m-chunk of 32
    const int d0 = blockIdx.y * 64;         // d base
    const int tx = threadIdx.x & 63;        // d within 64
    const int ty = threadIdx.x >> 6;        // 0..3
#pragma unroll
    for (int i = 0; i < 8; ++i) {
        const int row = ty + 4 * i;                  // 0..31
        const int m   = mc * 32 + row;
        T[row][tx] = (m < MEMN) ? mem[(size_t)m * DIM + d0 + tx] : 0.f;
    }
    __syncthreads();
    const int dbl = threadIdx.x >> 6;       // local 16-d block 0..3
    const int r   = threadIdx.x & 63;
    const int l16 = r >> 2, q = r & 3;
    unsigned short o[8];
#pragma unroll
    for (int j = 0; j < 8; ++j) o[j] = f2bf(T[q * 8 + j][dbl * 16 + l16]);
    *(uint4*)&dst[((size_t)(d0 / 16 + dbl) * 320 + mc) * 512 + r * 8] = *(const uint4*)o;
}

// ---------------------------------------------------------------------------
// W12T bf16 [768 n][1536 k]
// ---------------------------------------------------------------------------
__global__ void prep_w12T(const float* __restrict__ w1, unsigned short* __restrict__ wt)
{
    __shared__ float T[32][33];
    const int kb = blockIdx.x * 32, nb = blockIdx.y * 32;
    const int tx = threadIdx.x & 31, ty = threadIdx.x >> 5;
#pragma unroll
    for (int i = 0; i < 4; ++i) {
        int k = kb + ty + 8 * i;
        float v = w1[(size_t)(768 + k) * DIM + nb + tx];
        if (kb < 768) v += w1[(size_t)k * DIM + nb + tx];
        T[ty + 8 * i][tx] = v;
    }
    __syncthreads();
#pragma unroll
    for (int i = 0; i < 4; ++i) {
        int n = nb + ty + 8 * i;
        wt[(size_t)n * 1536 + kb + tx] = f2bf(T[tx][ty + 8 * i]);
    }
}

// ---------------------------------------------------------------------------
// W2T bf16 [768 n][768 k] = w2[k][n]
// ---------------------------------------------------------------------------
__global__ void prep_w2T(const float* __restrict__ w2, unsigned short* __restrict__ wt)
{
    __shared__ float T[32][33];
    const int kb = blockIdx.x * 32, nb = blockIdx.y * 32;
    const int tx = threadIdx.x & 31, ty = threadIdx.x >> 5;
#pragma unroll
    for (int i = 0; i < 4; ++i)
        T[ty + 8 * i][tx] = w2[(size_t)(kb + ty + 8 * i) * DIM + nb + tx];
    __syncthreads();
#pragma unroll
    for (int i = 0; i < 4; ++i)
        wt[(size_t)(nb + ty + 8 * i) * DIM + kb + tx] = f2bf(T[tx][ty + 8 * i]);
}

// ---------------------------------------------------------------------------
// Fused MFMA attention. Round-14: TQ 32 -> 64.
//  - 4 MFMAs per B-fragment load (was 2): halves required load-issue rate and
//    halves total L2 traffic (8 -> 4 GB). This attacks the measured bottleneck
//    (latency/issue-bound, MfmaUtil 14.6%) without deepening prefetch.
//  - Paid for with occupancy: launch_bounds(512, 2) -> 1 block/CU (130 KB LDS:
//    Qs 96K + Ps 32K + Lred 2K), 2 waves/SIMD, 256-reg unified budget.
//    Accounting: AGPR(oacc 96 + sacc 32)=128 + peak VGPR ~110 = ~238 < 256.
//  - phase-1 B depth-3/stream (distance-3 ~ 240cy cover at 2-wave step ~80cy);
//    phase-2 depth-2 (step time ~240cy at 2 waves -> distance-1 covers).
//  - plain-store epilogue kept (round-6 win); atomic fallback kept.
//  - Spill guard: WRITE_SIZE >= 500 MB = spill = revert.
// ---------------------------------------------------------------------------
template <int PLAIN>
__global__ __launch_bounds__(512, 2)
void attn_mfma(const unsigned short* __restrict__ qH, const unsigned short* __restrict__ memF,
               const unsigned short* __restrict__ memS,
               float* __restrict__ retrRaw, float* __restrict__ Lvec)
{
    __shared__ __align__(16) unsigned short Qs[64 * 768];   // 96 KB, xor-swizzled
    __shared__ __align__(16) unsigned short Ps[64 * 256];   // 32 KB, xor-swizzled
    __shared__ float Lred[8][64];                           // 2 KB, L block-reduce

    const int tid    = threadIdx.x;
    const int w      = tid >> 6;         // wave 0..7
    const int lane   = tid & 63;
    const int quad   = lane >> 4;        // 0..3
    const int l16    = lane & 15;
    const int fr     = ((l16 << 2) | quad) << 3;   // fragment-linear lane offset (ushorts)

    const int split = blockIdx.y;
    const int q0    = blockIdx.x * TQ;   // 0..8128 step 64

    const int dbase  = w * 96;           // phase-2 d-strip per wave
    const int mstrip = w * 32;           // phase-1 m-strip per wave

    // ---- stage Q tile (64 rows, bf16, swizzled) once ----
    {
        const int qr  = tid >> 3;            // 0..63
        const int db0 = tid & 7;
        const unsigned short* src = qH + (size_t)(q0 + qr) * DIM;
        const int sw = qr & 7;
#pragma unroll
        for (int i = 0; i < 12; ++i) {
            int db = db0 + i * 8;            // 0..95 (blocks of 8 bf16)
            uint4 v = *(const uint4*)&src[db * 8];
            *(uint4*)&Qs[qr * 768 + ((db ^ sw) << 3)] = v;
        }
    }
    __syncthreads();

    f32x4 oacc[4][6];
#pragma unroll
    for (int a = 0; a < 4; ++a)
#pragma unroll
        for (int b = 0; b < 6; ++b) oacc[a][b] = (f32x4){0.f, 0.f, 0.f, 0.f};
    float lsum[4][4];
#pragma unroll
    for (int a = 0; a < 4; ++a)
#pragma unroll
        for (int r = 0; r < 4; ++r) lsum[a][r] = 0.f;

    const int xsw = l16 & 7;   // rows l16,16+l16,32+l16,48+l16 share (row&7)=xsw

    for (int st = 0; st < TILES_PER_SPLIT; ++st) {
        const int m0  = (split * TILES_PER_SPLIT + st) * TM;
        const int mc0 = m0 >> 5;                          // m-chunk base for phase 2

        // ---- phase 1: S[64 x 256]; wave w covers m-strip mstrip..+32 ----
        f32x4 sacc[4][2];
#pragma unroll
        for (int a = 0; a < 4; ++a)
#pragma unroll
            for (int b = 0; b < 2; ++b) sacc[a][b] = (f32x4){0.f, 0.f, 0.f, 0.f};

        const unsigned short* fb0 = memF + ((size_t)(m0 >> 4) + 2 * w) * 12288 + fr;
        const unsigned short* fb1 = fb0 + 12288;

        bf16x8 pb0[3], pb1[3];
#pragma unroll
        for (int i = 0; i < 3; ++i) {
            pb0[i] = *(const bf16x8*)(fb0 + i * 512);
            pb1[i] = *(const bf16x8*)(fb1 + i * 512);
        }

#pragma unroll
        for (int ks = 0; ks < 24; ++ks) {
            const int xq = (((ks << 2) + quad) ^ xsw) << 3;
            bf16x8 a0 = *(const bf16x8*)&Qs[l16 * 768 + xq];
            bf16x8 a1 = *(const bf16x8*)&Qs[(16 + l16) * 768 + xq];
            bf16x8 a2 = *(const bf16x8*)&Qs[(32 + l16) * 768 + xq];
            bf16x8 a3 = *(const bf16x8*)&Qs[(48 + l16) * 768 + xq];
            bf16x8 b0 = pb0[ks % 3];
            bf16x8 b1 = pb1[ks % 3];
            sacc[0][0] = __builtin_amdgcn_mfma_f32_16x16x32_bf16(a0, b0, sacc[0][0], 0, 0, 0);
            sacc[1][0] = __builtin_amdgcn_mfma_f32_16x16x32_bf16(a1, b0, sacc[1][0], 0, 0, 0);
            sacc[2][0] = __builtin_amdgcn_mfma_f32_16x16x32_bf16(a2, b0, sacc[2][0], 0, 0, 0);
            sacc[3][0] = __builtin_amdgcn_mfma_f32_16x16x32_bf16(a3, b0, sacc[3][0], 0, 0, 0);
            sacc[0][1] = __builtin_amdgcn_mfma_f32_16x16x32_bf16(a0, b1, sacc[0][1], 0, 0, 0);
            sacc[1][1] = __builtin_amdgcn_mfma_f32_16x16x32_bf16(a1, b1, sacc[1][1], 0, 0, 0);
            sacc[2][1] = __builtin_amdgcn_mfma_f32_16x16x32_bf16(a2, b1, sacc[2][1], 0, 0, 0);
            sacc[3][1] = __builtin_amdgcn_mfma_f32_16x16x32_bf16(a3, b1, sacc[3][1], 0, 0, 0);
            if (ks < 21) {
                pb0[ks % 3] = *(const bf16x8*)(fb0 + (ks + 3) * 512);
                pb1[ks % 3] = *(const bf16x8*)(fb1 + (ks + 3) * 512);
            }
        }

        __syncthreads();   // barrier A: all waves done reading previous tile's Ps

        // ---- exp + P->LDS (bf16, swizzled) + row-sum accumulation ----
#pragma unroll
        for (int qt = 0; qt < 4; ++qt)
#pragma unroll
            for (int mt = 0; mt < 2; ++mt) {
                const int mloc = mstrip + mt * 16 + l16;      // 0..255
                const bool ok  = (m0 + mloc) < MEMN;
#pragma unroll
                for (int r = 0; r < 4; ++r) {
                    float p = ok ? __expf(sacc[qt][mt][r] * SCALE) : 0.f;
                    const int q = qt * 16 + quad * 4 + r;     // 0..63
                    lsum[qt][r] += p;
                    Ps[q * 256 + (((mloc >> 3) ^ (q & 7)) << 3) + (mloc & 7)] = f2bf(p);
                }
            }

        __syncthreads();   // barrier B: Ps complete

        // ---- phase 2: O += P * Mem; depth-2 register prefetch of B-frags ----
        const unsigned short* msp = memS + ((size_t)(6 * w) * 320 + mc0) * 512 + fr;
        bf16x8 cb[2][6];
#pragma unroll
        for (int nt = 0; nt < 6; ++nt) {
            cb[0][nt] = *(const bf16x8*)(msp + (size_t)nt * 163840);
            cb[1][nt] = *(const bf16x8*)(msp + (size_t)nt * 163840 + 512);
        }

#pragma unroll
        for (int ks = 0; ks < 8; ++ks) {
            const int xp = (((ks << 2) + quad) ^ xsw) << 3;
            bf16x8 pa0 = *(const bf16x8*)&Ps[l16 * 256 + xp];
            bf16x8 pa1 = *(const bf16x8*)&Ps[(16 + l16) * 256 + xp];
            bf16x8 pa2 = *(const bf16x8*)&Ps[(32 + l16) * 256 + xp];
            bf16x8 pa3 = *(const bf16x8*)&Ps[(48 + l16) * 256 + xp];
            const bool dopf = (ks < 6);
#pragma unroll
            for (int nt = 0; nt < 6; ++nt) {
                oacc[0][nt] = __builtin_amdgcn_mfma_f32_16x16x32_bf16(pa0, cb[ks & 1][nt], oacc[0][nt], 0, 0, 0);
                oacc[1][nt] = __builtin_amdgcn_mfma_f32_16x16x32_bf16(pa1, cb[ks & 1][nt], oacc[1][nt], 0, 0, 0);
                oacc[2][nt] = __builtin_amdgcn_mfma_f32_16x16x32_bf16(pa2, cb[ks & 1][nt], oacc[2][nt], 0, 0, 0);
                oacc[3][nt] = __builtin_amdgcn_mfma_f32_16x16x32_bf16(pa3, cb[ks & 1][nt], oacc[3][nt], 0, 0, 0);
                if (dopf) cb[ks & 1][nt] = *(const bf16x8*)(msp + (size_t)nt * 163840 + (ks + 2) * 512);
            }
        }
    }

    // ---- epilogue: combine O and L across splits ----
    float* ob = retrRaw + (PLAIN ? (size_t)split * ((size_t)N_TOK * DIM) : (size_t)0);
#pragma unroll
    for (int qt = 0; qt < 4; ++qt)
#pragma unroll
        for (int nt = 0; nt < 6; ++nt)
#pragma unroll
            for (int r = 0; r < 4; ++r) {
                const size_t idx = (size_t)(q0 + qt * 16 + quad * 4 + r) * DIM + dbase + nt * 16 + l16;
                if (PLAIN)
                    ob[idx] = oacc[qt][nt][r];
                else
                    __hip_atomic_fetch_add(&ob[idx], oacc[qt][nt][r],
                                           __ATOMIC_RELAXED, __HIP_MEMORY_SCOPE_AGENT);
            }

#pragma unroll
    for (int qt = 0; qt < 4; ++qt)
#pragma unroll
        for (int r = 0; r < 4; ++r) {
            float v = lsum[qt][r];
#pragma unroll
            for (int off = 1; off < 16; off <<= 1) v += __shfl_xor(v, off);
            if (l16 == 0) {
                if (PLAIN)
                    Lred[w][qt * 16 + quad * 4 + r] = v;
                else
                    __hip_atomic_fetch_add(&Lvec[q0 + qt * 16 + quad * 4 + r], v,
                                           __ATOMIC_RELAXED, __HIP_MEMORY_SCOPE_AGENT);
            }
        }
    if (PLAIN) {
        __syncthreads();
        if (tid < 64) {
            float s = 0.f;
#pragma unroll
            for (int ww = 0; ww < 8; ++ww) s += Lred[ww][tid];
            Lvec[(size_t)split * N_TOK + q0 + tid] = s;
        }
    }
}

// ---------------------------------------------------------------------------
// Normalize retrieved, compute gate, build XRb = bf16([cs + g*r | r]).
// PLAIN=1: retrRaw/Lvec hold 2 split-partials, summed here.
// ---------------------------------------------------------------------------
template <int PLAIN>
__global__ __launch_bounds__(256)
void finalize_xr(const float* __restrict__ retrRaw, const float* __restrict__ Lvec,
                 const float* __restrict__ cs, const float* __restrict__ gw,
                 const float* __restrict__ gb, unsigned short* __restrict__ XRb)
{
    const int lane = threadIdx.x & 63;
    const int row  = blockIdx.x * 4 + (threadIdx.x >> 6);
    const float lv = PLAIN ? (Lvec[row] + Lvec[N_TOK + row]) : Lvec[row];
    const float rl = 1.0f / lv;
    const float* rr  = retrRaw + (size_t)row * DIM;
    const float* rr1 = retrRaw + (size_t)N_TOK * DIM + (size_t)row * DIM;
    const float* cr = cs + (size_t)row * DIM;

    float4 rv[3], cv[3];
    float d = 0.f;
#pragma unroll
    for (int i = 0; i < 3; ++i) {
        const int c4 = i * 256 + lane * 4;
        float4 r = *(const float4*)&rr[c4];
        if (PLAIN) {
            float4 r1 = *(const float4*)&rr1[c4];
            r.x += r1.x; r.y += r1.y; r.z += r1.z; r.w += r1.w;
        }
        r.x *= rl; r.y *= rl; r.z *= rl; r.w *= rl;
        float4 c = *(const float4*)&cr[c4];
        float4 g1 = *(const float4*)&gw[c4];
        float4 g2 = *(const float4*)&gw[DIM + c4];
        d += c.x * g1.x + c.y * g1.y + c.z * g1.z + c.w * g1.w;
        d += r.x * g2.x + r.y * g2.y + r.z * g2.z + r.w * g2.w;
        rv[i] = r; cv[i] = c;
    }
#pragma unroll
    for (int off = 32; off > 0; off >>= 1) d += __shfl_xor(d, off);
    d += gb[0];
    const float g = 1.0f / (1.0f + __expf(-d));

    unsigned short* xb = XRb + (size_t)row * 1536;
#pragma unroll
    for (int i = 0; i < 3; ++i) {
        const int c4 = i * 256 + lane * 4;
        ushort4 xo, ro;
        xo.x = f2bf(cv[i].x + g * rv[i].x); xo.y = f2bf(cv[i].y + g * rv[i].y);
        xo.z = f2bf(cv[i].z + g * rv[i].z); xo.w = f2bf(cv[i].w + g * rv[i].w);
        ro.x = f2bf(rv[i].x); ro.y = f2bf(rv[i].y);
        ro.z = f2bf(rv[i].z); ro.w = f2bf(rv[i].w);
        *(ushort4*)&xb[c4] = xo;
        *(ushort4*)&xb[DIM + c4] = ro;
    }
}

// ---------------------------------------------------------------------------
// MFMA GEMM: C[M x 768] = A[M x K](bf16) @ WT[768 x K](bf16, [n][k]) + bias.
// ---------------------------------------------------------------------------
template <int K, int ACT>
__global__ __launch_bounds__(256, 2)
void gemm_mfma(const unsigned short* __restrict__ A, const unsigned short* __restrict__ WT,
               const float* __restrict__ bias, const float* __restrict__ gamma,
               const float* __restrict__ beta, void* __restrict__ outv)
{
    __shared__ __align__(16) unsigned short As[16 * 256];   // 8 KB, xor-swizzled
    __shared__ float red[2][4][16];

    const int tid  = threadIdx.x;
    const int w    = tid >> 6;
    const int lane = tid & 63;
    const int quad = lane >> 4;
    const int l16  = lane & 15;
    const int row0 = blockIdx.x * 16;
    const int nbase = w * 192;
    const int xsw3 = l16 & 7;

    f32x4 acc[12];
#pragma unroll
    for (int nt = 0; nt < 12; ++nt) acc[nt] = (f32x4){0.f, 0.f, 0.f, 0.f};

    bf16x8 b[12];
#pragma unroll
    for (int nt = 0; nt < 12; ++nt)
        b[nt] = *(const bf16x8*)&WT[(size_t)(nbase + nt * 16 + l16) * K + quad * 8];

    for (int ch = 0; ch < K / 256; ++ch) {
        const int kc0 = ch * 256;
        __syncthreads();
#pragma unroll
        for (int i = 0; i < 2; ++i) {
            const int f = tid + i * 256;
            const int r = f >> 5, kb8 = f & 31;
            *(uint4*)&As[r * 256 + ((kb8 ^ (r & 7)) << 3)] =
                *(const uint4*)&A[(size_t)(row0 + r) * K + kc0 + kb8 * 8];
        }
        __syncthreads();
#pragma unroll
        for (int ks = 0; ks < 8; ++ks) {
            const int kc = ks * 32;
            bf16x8 af = *(const bf16x8*)&As[l16 * 256 + ((((kc >> 3) + quad) ^ xsw3) << 3)];
            int gn = kc0 + kc + 32;
            if (gn >= K) gn = 0;                      // dummy wrap (harmless)
#pragma unroll
            for (int nt = 0; nt < 12; ++nt) {
                acc[nt] = __builtin_amdgcn_mfma_f32_16x16x32_bf16(af, b[nt], acc[nt], 0, 0, 0);
                b[nt] = *(const bf16x8*)&WT[(size_t)(nbase + nt * 16 + l16) * K + gn + quad * 8];
            }
        }
    }

    float bv[12];
#pragma unroll
    for (int nt = 0; nt < 12; ++nt) bv[nt] = bias[nbase + nt * 16 + l16];

    if (ACT == 0) {
        unsigned short* out = (unsigned short*)outv;
#pragma unroll
        for (int nt = 0; nt < 12; ++nt)
#pragma unroll
            for (int r = 0; r < 4; ++r) {
                const int row = row0 + quad * 4 + r;
                float v = acc[nt][r] + bv[nt];
                v = 0.5f * v * (1.0f + erff(v * 0.7071067811865476f));
                out[(size_t)row * DIM + nbase + nt * 16 + l16] = f2bf(v);
            }
    } else {
        float* out = (float*)outv;
        float v[12][4];
        float s1[4] = {0.f, 0.f, 0.f, 0.f}, s2[4] = {0.f, 0.f, 0.f, 0.f};
#pragma unroll
        for (int nt = 0; nt < 12; ++nt)
#pragma unroll
            for (int r = 0; r < 4; ++r) {
                float t = acc[nt][r] + bv[nt];
                v[nt][r] = t;
                s1[r] += t;
                s2[r] += t * t;
            }
#pragma unroll
        for (int r = 0; r < 4; ++r) {
#pragma unroll
            for (int off = 1; off < 16; off <<= 1) {
                s1[r] += __shfl_xor(s1[r], off);
                s2[r] += __shfl_xor(s2[r], off);
            }
            if (l16 == 0) {
                red[0][w][quad * 4 + r] = s1[r];
                red[1][w][quad * 4 + r] = s2[r];
            }
        }
        __syncthreads();
#pragma unroll
        for (int r = 0; r < 4; ++r) {
            const int rl16 = quad * 4 + r;
            const float t1 = red[0][0][rl16] + red[0][1][rl16] + red[0][2][rl16] + red[0][3][rl16];
            const float t2 = red[1][0][rl16] + red[1][1][rl16] + red[1][2][rl16] + red[1][3][rl16];
            const float mu  = t1 * (1.0f / 768.0f);
            const float var = fmaxf(t2 * (1.0f / 768.0f) - mu * mu, 0.f);
            const float rs  = rsqrtf(var + 1e-5f);
            const int row = row0 + rl16;
#pragma unroll
            for (int nt = 0; nt < 12; ++nt) {
                const int col = nbase + nt * 16 + l16;
                out[(size_t)row * DIM + col] = (v[nt][r] - mu) * rs * gamma[col] + beta[col];
            }
        }
    }
}

// ---------------------------------------------------------------------------
extern "C" void kernel_launch(void* const* d_in, const int* in_sizes, int n_in,
                              void* d_out, int out_size, void* d_ws, size_t ws_size,
                              hipStream_t stream)
{
    const float* cs  = (const float*)d_in[0];
    const float* mem = (const float*)d_in[1];
    const float* gw  = (const float*)d_in[2];
    const float* gb  = (const float*)d_in[3];
    const float* fw1 = (const float*)d_in[4];
    const float* fb1 = (const float*)d_in[5];
    const float* fw2 = (const float*)d_in[6];
    const float* fb2 = (const float*)d_in[7];
    const float* gam = (const float*)d_in[8];
    const float* bet = (const float*)d_in[9];
    float* out = (float*)d_out;

    char* ws = (char*)d_ws;
    // Layout A (atomic fallback, ~72.8 MB) / Layout B (plain, ~98 MB):
    const size_t PLAIN_WS = 97976320;
    const bool plain = (ws_size >= PLAIN_WS);

    unsigned short* memF = (unsigned short*)ws;                 // 15,728,640
    unsigned short* memS = (unsigned short*)(ws + 15728640);    // 15,728,640
    unsigned short* qH   = (unsigned short*)(ws + 31457280);    // 12,582,912
    float*          retr = (float*)(ws + 44040192);             // A: 25,165,824 / B: 50,331,648
    float*          Lvec;
    unsigned short* w12T;
    unsigned short* w2T;
    if (plain) {
        Lvec = (float*)(ws + 94371840);            // 65,536 (2 splits)
        w12T = (unsigned short*)(ws + 94437376);   // 2,359,296
        w2T  = (unsigned short*)(ws + 96796672);   // 1,179,648 -> end 97,976,320
    } else {
        Lvec = (float*)(ws + 69206016);            // 32,768
        w12T = (unsigned short*)(ws + 69238784);   // 2,359,296
        w2T  = (unsigned short*)(ws + 71598080);   // 1,179,648 -> end 72,777,728
    }
    unsigned short* XRb  = (unsigned short*)ws;                 // alias memF+memS (dead after attn)
    unsigned short* hb   = qH;                                  // alias qH (dead after attn)

    if (!plain)
        hipMemsetAsync(retr, 0, 25165824 + 32768, stream);      // atomic path needs zeroed accum

    cvt_memF<<<MEMP / 16, 256, 0, stream>>>(mem, memF);
    cvt_qH<<<(N_TOK * DIM) / (256 * 4), 256, 0, stream>>>(cs, qH);
    cvt_memS<<<dim3(MEMP / 32, DIM / 64), 256, 0, stream>>>(mem, memS);
    prep_w12T<<<dim3(48, 24), 256, 0, stream>>>(fw1, w12T);
    prep_w2T<<<dim3(24, 24), 256, 0, stream>>>(fw2, w2T);

    if (plain) {
        attn_mfma<1><<<dim3(N_TOK / TQ, NSPLIT), 512, 0, stream>>>(qH, memF, memS, retr, Lvec);
        finalize_xr<1><<<N_TOK / 4, 256, 0, stream>>>(retr, Lvec, cs, gw, gb, XRb);
    } else {
        attn_mfma<0><<<dim3(N_TOK / TQ, NSPLIT), 512, 0, stream>>>(qH, memF, memS, retr, Lvec);
        finalize_xr<0><<<N_TOK / 4, 256, 0, stream>>>(retr, Lvec, cs, gw, gb, XRb);
    }
    gemm_mfma<1536, 0><<<N_TOK / 16, 256, 0, stream>>>(XRb, w12T, fb1, nullptr, nullptr, hb);
    gemm_mfma<768, 1><<<N_TOK / 16, 256, 0, stream>>>(hb, w2T, fb2, gam, bet, out);
}

// Round 8
// 938.614 us; speedup vs baseline: 1.1817x; 1.1817x over previous
//
#include <hip/hip_runtime.h>
#include <math.h>

#define N_TOK 8192
#define DIM   768
#define MEMN  10000
#define MEMP  10240            // padded to 40*256
#define TQ    64
#define TM    256
#define NSPLIT 2
#define TILES_PER_SPLIT 20

constexpr float SCALE = 0.036084391824351615f;  // 1/sqrt(768)

typedef short bf16x8 __attribute__((ext_vector_type(8)));
typedef float f32x4  __attribute__((ext_vector_type(4)));

__device__ __forceinline__ unsigned short f2bf(float f) {
    unsigned u = __float_as_uint(f);
    unsigned r = (u + 0x7fffu + ((u >> 16) & 1u)) >> 16;   // RTN-even
    return (unsigned short)r;
}

// ---------------------------------------------------------------------------
// memF: fragment-linear bf16 layout of mem for phase 1 (QK^T B-operand).
// slot(mb, kc, l16, quad, j) = mem[mb*16 + l16][kc*32 + quad*8 + j]
// offset (ushorts) = (mb*24 + kc)*512 + (l16*4 + quad)*8
// ---------------------------------------------------------------------------
__global__ void cvt_memF(const float* __restrict__ mem, unsigned short* __restrict__ dst)
{
    const int mb = blockIdx.x;                       // 0..639
    const bool zero = (mb >= MEMN / 16);             // 625 exact blocks valid
#pragma unroll
    for (int it = 0; it < 6; ++it) {
        const int s   = it * 256 + threadIdx.x;      // 0..1535
        const int kc  = s >> 6;
        const int r   = s & 63;
        const int l16 = r >> 2, q = r & 3;
        unsigned short o[8];
        if (!zero) {
            const float* src = &mem[(size_t)(mb * 16 + l16) * DIM + kc * 32 + q * 8];
            float4 v0 = *(const float4*)src;
            float4 v1 = *(const float4*)(src + 4);
            o[0] = f2bf(v0.x); o[1] = f2bf(v0.y); o[2] = f2bf(v0.z); o[3] = f2bf(v0.w);
            o[4] = f2bf(v1.x); o[5] = f2bf(v1.y); o[6] = f2bf(v1.z); o[7] = f2bf(v1.w);
        } else {
#pragma unroll
            for (int j = 0; j < 8; ++j) o[j] = 0;
        }
        *(uint4*)&dst[((size_t)mb * 24 + kc) * 512 + r * 8] = *(const uint4*)o;
    }
}

// ---------------------------------------------------------------------------
// Q fp32 -> bf16 (row-major, same layout)
// ---------------------------------------------------------------------------
__global__ void cvt_qH(const float* __restrict__ q, unsigned short* __restrict__ dst)
{
    const size_t i = ((size_t)blockIdx.x * 256 + threadIdx.x) * 4;
    float4 v = *(const float4*)&q[i];
    ushort4 o;
    o.x = f2bf(v.x); o.y = f2bf(v.y); o.z = f2bf(v.z); o.w = f2bf(v.w);
    *(ushort4*)&dst[i] = o;
}

// ---------------------------------------------------------------------------
// memS: fragment-linear transposed layout for phase 2 (PV B-operand).
// slot(db, mc, l16, quad, j) = mem[mc*32 + quad*8 + j][db*16 + l16]  (0 if m>=10000)
// offset (ushorts) = (db*320 + mc)*512 + (l16*4 + quad)*8
// ---------------------------------------------------------------------------
__global__ void cvt_memS(const float* __restrict__ mem, unsigned short* __restrict__ dst)
{
    __shared__ float T[32][65];
    const int mc = blockIdx.x;              // m-chunk of 32
    const int d0 = blockIdx.y * 64;         // d base
    const int tx = threadIdx.x & 63;        // d within 64
    const int ty = threadIdx.x >> 6;        // 0..3
#pragma unroll
    for (int i = 0; i < 8; ++i) {
        const int row = ty + 4 * i;                  // 0..31
        const int m   = mc * 32 + row;
        T[row][tx] = (m < MEMN) ? mem[(size_t)m * DIM + d0 + tx] : 0.f;
    }
    __syncthreads();
    const int dbl = threadIdx.x >> 6;       // local 16-d block 0..3
    const int r   = threadIdx.x & 63;
    const int l16 = r >> 2, q = r & 3;
    unsigned short o[8];
#pragma unroll
    for (int j = 0; j < 8; ++j) o[j] = f2bf(T[q * 8 + j][dbl * 16 + l16]);
    *(uint4*)&dst[((size_t)(d0 / 16 + dbl) * 320 + mc) * 512 + r * 8] = *(const uint4*)o;
}

// ---------------------------------------------------------------------------
// W12T bf16 [768 n][1536 k]
// ---------------------------------------------------------------------------
__global__ void prep_w12T(const float* __restrict__ w1, unsigned short* __restrict__ wt)
{
    __shared__ float T[32][33];
    const int kb = blockIdx.x * 32, nb = blockIdx.y * 32;
    const int tx = threadIdx.x & 31, ty = threadIdx.x >> 5;
#pragma unroll
    for (int i = 0; i < 4; ++i) {
        int k = kb + ty + 8 * i;
        float v = w1[(size_t)(768 + k) * DIM + nb + tx];
        if (kb < 768) v += w1[(size_t)k * DIM + nb + tx];
        T[ty + 8 * i][tx] = v;
    }
    __syncthreads();
#pragma unroll
    for (int i = 0; i < 4; ++i) {
        int n = nb + ty + 8 * i;
        wt[(size_t)n * 1536 + kb + tx] = f2bf(T[tx][ty + 8 * i]);
    }
}

// ---------------------------------------------------------------------------
// W2T bf16 [768 n][768 k] = w2[k][n]
// ---------------------------------------------------------------------------
__global__ void prep_w2T(const float* __restrict__ w2, unsigned short* __restrict__ wt)
{
    __shared__ float T[32][33];
    const int kb = blockIdx.x * 32, nb = blockIdx.y * 32;
    const int tx = threadIdx.x & 31, ty = threadIdx.x >> 5;
#pragma unroll
    for (int i = 0; i < 4; ++i)
        T[ty + 8 * i][tx] = w2[(size_t)(kb + ty + 8 * i) * DIM + nb + tx];
    __syncthreads();
#pragma unroll
    for (int i = 0; i < 4; ++i)
        wt[(size_t)(nb + ty + 8 * i) * DIM + kb + tx] = f2bf(T[tx][ty + 8 * i]);
}

// ---------------------------------------------------------------------------
// Fused MFMA attention. Round-15: TQ=64 with SIXTEEN waves (1024 thr).
//  - Keeps round-7's halved per-wave load count (48 loads/wave/tile, 4 MFMAs
//    per B-fragment) AND restores 4 waves/SIMD TLP (round 7 proved traffic
//    isn't the limit; the product TLP x in-flight-loads is).
//  - Per-wave partition shrinks: phase 1 = 16-row m-strip (single B-stream,
//    sacc[4]); phase 2 = 48-col d-strip (oacc[4][3], cb[2][3]).
//    Register peak is lighter than round-6's proven-fit shapes -> 128-reg
//    budget at launch_bounds(1024,4) expected to hold. Spill guard:
//    WRITE_SIZE >= 500 MB => revert.
//  - LDS 132 KB (Qs 96K + Ps 32K + Lred 4K), 1 block/CU, grid = 256 blocks.
//  - plain-store epilogue kept (round-6 win); atomic fallback kept.
// ---------------------------------------------------------------------------
template <int PLAIN>
__global__ __launch_bounds__(1024, 4)
void attn_mfma(const unsigned short* __restrict__ qH, const unsigned short* __restrict__ memF,
               const unsigned short* __restrict__ memS,
               float* __restrict__ retrRaw, float* __restrict__ Lvec)
{
    __shared__ __align__(16) unsigned short Qs[64 * 768];   // 96 KB, xor-swizzled
    __shared__ __align__(16) unsigned short Ps[64 * 256];   // 32 KB, xor-swizzled
    __shared__ float Lred[16][64];                          // 4 KB, L block-reduce

    const int tid    = threadIdx.x;
    const int w      = tid >> 6;         // wave 0..15
    const int lane   = tid & 63;
    const int quad   = lane >> 4;        // 0..3
    const int l16    = lane & 15;
    const int fr     = ((l16 << 2) | quad) << 3;   // fragment-linear lane offset (ushorts)

    const int split = blockIdx.y;
    const int q0    = blockIdx.x * TQ;   // 0..8128 step 64

    const int dbase  = w * 48;           // phase-2 d-strip per wave (3 x 16)
    const int mstrip = w * 16;           // phase-1 m-strip per wave (1 x 16)

    // ---- stage Q tile (64 rows, bf16, swizzled) once ----
    {
        const int qr  = tid >> 4;            // 0..63
        const int db0 = tid & 15;
        const unsigned short* src = qH + (size_t)(q0 + qr) * DIM;
        const int sw = qr & 7;
#pragma unroll
        for (int i = 0; i < 6; ++i) {
            int db = db0 + i * 16;           // 0..95 (blocks of 8 bf16)
            uint4 v = *(const uint4*)&src[db * 8];
            *(uint4*)&Qs[qr * 768 + ((db ^ sw) << 3)] = v;
        }
    }
    __syncthreads();

    f32x4 oacc[4][3];
#pragma unroll
    for (int a = 0; a < 4; ++a)
#pragma unroll
        for (int b = 0; b < 3; ++b) oacc[a][b] = (f32x4){0.f, 0.f, 0.f, 0.f};
    float lsum[4][4];
#pragma unroll
    for (int a = 0; a < 4; ++a)
#pragma unroll
        for (int r = 0; r < 4; ++r) lsum[a][r] = 0.f;

    const int xsw = l16 & 7;   // rows l16,16+l16,32+l16,48+l16 share (row&7)

    for (int st = 0; st < TILES_PER_SPLIT; ++st) {
        const int m0  = (split * TILES_PER_SPLIT + st) * TM;
        const int mc0 = m0 >> 5;                          // m-chunk base for phase 2

        // ---- phase 1: S[64 x 256]; wave w covers m-strip mstrip..+16 ----
        f32x4 sacc[4];
#pragma unroll
        for (int a = 0; a < 4; ++a) sacc[a] = (f32x4){0.f, 0.f, 0.f, 0.f};

        const unsigned short* fb = memF + ((size_t)(m0 >> 4) + w) * 12288 + fr;

        bf16x8 pb[2];
        pb[0] = *(const bf16x8*)(fb);
        pb[1] = *(const bf16x8*)(fb + 512);

#pragma unroll
        for (int ks = 0; ks < 24; ++ks) {
            const int xq = (((ks << 2) + quad) ^ xsw) << 3;
            bf16x8 a0 = *(const bf16x8*)&Qs[l16 * 768 + xq];
            bf16x8 a1 = *(const bf16x8*)&Qs[(16 + l16) * 768 + xq];
            bf16x8 a2 = *(const bf16x8*)&Qs[(32 + l16) * 768 + xq];
            bf16x8 a3 = *(const bf16x8*)&Qs[(48 + l16) * 768 + xq];
            bf16x8 b = pb[ks & 1];
            sacc[0] = __builtin_amdgcn_mfma_f32_16x16x32_bf16(a0, b, sacc[0], 0, 0, 0);
            sacc[1] = __builtin_amdgcn_mfma_f32_16x16x32_bf16(a1, b, sacc[1], 0, 0, 0);
            sacc[2] = __builtin_amdgcn_mfma_f32_16x16x32_bf16(a2, b, sacc[2], 0, 0, 0);
            sacc[3] = __builtin_amdgcn_mfma_f32_16x16x32_bf16(a3, b, sacc[3], 0, 0, 0);
            if (ks < 22) pb[ks & 1] = *(const bf16x8*)(fb + (ks + 2) * 512);
        }

        __syncthreads();   // barrier A: all waves done reading previous tile's Ps

        // ---- exp + P->LDS (bf16, swizzled) + row-sum accumulation ----
        {
            const int mloc = mstrip + l16;               // 0..255
            const bool ok  = (m0 + mloc) < MEMN;
#pragma unroll
            for (int qt = 0; qt < 4; ++qt)
#pragma unroll
                for (int r = 0; r < 4; ++r) {
                    float p = ok ? __expf(sacc[qt][r] * SCALE) : 0.f;
                    const int q = qt * 16 + quad * 4 + r;     // 0..63
                    lsum[qt][r] += p;
                    Ps[q * 256 + (((mloc >> 3) ^ (q & 7)) << 3) + (mloc & 7)] = f2bf(p);
                }
        }

        __syncthreads();   // barrier B: Ps complete

        // ---- phase 2: O += P * Mem; depth-2 register prefetch of B-frags ----
        const unsigned short* msp = memS + ((size_t)(3 * w) * 320 + mc0) * 512 + fr;
        bf16x8 cb[2][3];
#pragma unroll
        for (int nt = 0; nt < 3; ++nt) {
            cb[0][nt] = *(const bf16x8*)(msp + (size_t)nt * 163840);
            cb[1][nt] = *(const bf16x8*)(msp + (size_t)nt * 163840 + 512);
        }

#pragma unroll
        for (int ks = 0; ks < 8; ++ks) {
            const int xp = (((ks << 2) + quad) ^ xsw) << 3;
            bf16x8 pa0 = *(const bf16x8*)&Ps[l16 * 256 + xp];
            bf16x8 pa1 = *(const bf16x8*)&Ps[(16 + l16) * 256 + xp];
            bf16x8 pa2 = *(const bf16x8*)&Ps[(32 + l16) * 256 + xp];
            bf16x8 pa3 = *(const bf16x8*)&Ps[(48 + l16) * 256 + xp];
            const bool dopf = (ks < 6);
#pragma unroll
            for (int nt = 0; nt < 3; ++nt) {
                oacc[0][nt] = __builtin_amdgcn_mfma_f32_16x16x32_bf16(pa0, cb[ks & 1][nt], oacc[0][nt], 0, 0, 0);
                oacc[1][nt] = __builtin_amdgcn_mfma_f32_16x16x32_bf16(pa1, cb[ks & 1][nt], oacc[1][nt], 0, 0, 0);
                oacc[2][nt] = __builtin_amdgcn_mfma_f32_16x16x32_bf16(pa2, cb[ks & 1][nt], oacc[2][nt], 0, 0, 0);
                oacc[3][nt] = __builtin_amdgcn_mfma_f32_16x16x32_bf16(pa3, cb[ks & 1][nt], oacc[3][nt], 0, 0, 0);
                if (dopf) cb[ks & 1][nt] = *(const bf16x8*)(msp + (size_t)nt * 163840 + (ks + 2) * 512);
            }
        }
    }

    // ---- epilogue: combine O and L across splits ----
    float* ob = retrRaw + (PLAIN ? (size_t)split * ((size_t)N_TOK * DIM) : (size_t)0);
#pragma unroll
    for (int qt = 0; qt < 4; ++qt)
#pragma unroll
        for (int nt = 0; nt < 3; ++nt)
#pragma unroll
            for (int r = 0; r < 4; ++r) {
                const size_t idx = (size_t)(q0 + qt * 16 + quad * 4 + r) * DIM + dbase + nt * 16 + l16;
                if (PLAIN)
                    ob[idx] = oacc[qt][nt][r];
                else
                    __hip_atomic_fetch_add(&ob[idx], oacc[qt][nt][r],
                                           __ATOMIC_RELAXED, __HIP_MEMORY_SCOPE_AGENT);
            }

#pragma unroll
    for (int qt = 0; qt < 4; ++qt)
#pragma unroll
        for (int r = 0; r < 4; ++r) {
            float v = lsum[qt][r];
#pragma unroll
            for (int off = 1; off < 16; off <<= 1) v += __shfl_xor(v, off);
            if (l16 == 0) {
                if (PLAIN)
                    Lred[w][qt * 16 + quad * 4 + r] = v;
                else
                    __hip_atomic_fetch_add(&Lvec[q0 + qt * 16 + quad * 4 + r], v,
                                           __ATOMIC_RELAXED, __HIP_MEMORY_SCOPE_AGENT);
            }
        }
    if (PLAIN) {
        __syncthreads();
        if (tid < 64) {
            float s = 0.f;
#pragma unroll
            for (int ww = 0; ww < 16; ++ww) s += Lred[ww][tid];
            Lvec[(size_t)split * N_TOK + q0 + tid] = s;
        }
    }
}

// ---------------------------------------------------------------------------
// Normalize retrieved, compute gate, build XRb = bf16([cs + g*r | r]).
// PLAIN=1: retrRaw/Lvec hold 2 split-partials, summed here.
// ---------------------------------------------------------------------------
template <int PLAIN>
__global__ __launch_bounds__(256)
void finalize_xr(const float* __restrict__ retrRaw, const float* __restrict__ Lvec,
                 const float* __restrict__ cs, const float* __restrict__ gw,
                 const float* __restrict__ gb, unsigned short* __restrict__ XRb)
{
    const int lane = threadIdx.x & 63;
    const int row  = blockIdx.x * 4 + (threadIdx.x >> 6);
    const float lv = PLAIN ? (Lvec[row] + Lvec[N_TOK + row]) : Lvec[row];
    const float rl = 1.0f / lv;
    const float* rr  = retrRaw + (size_t)row * DIM;
    const float* rr1 = retrRaw + (size_t)N_TOK * DIM + (size_t)row * DIM;
    const float* cr = cs + (size_t)row * DIM;

    float4 rv[3], cv[3];
    float d = 0.f;
#pragma unroll
    for (int i = 0; i < 3; ++i) {
        const int c4 = i * 256 + lane * 4;
        float4 r = *(const float4*)&rr[c4];
        if (PLAIN) {
            float4 r1 = *(const float4*)&rr1[c4];
            r.x += r1.x; r.y += r1.y; r.z += r1.z; r.w += r1.w;
        }
        r.x *= rl; r.y *= rl; r.z *= rl; r.w *= rl;
        float4 c = *(const float4*)&cr[c4];
        float4 g1 = *(const float4*)&gw[c4];
        float4 g2 = *(const float4*)&gw[DIM + c4];
        d += c.x * g1.x + c.y * g1.y + c.z * g1.z + c.w * g1.w;
        d += r.x * g2.x + r.y * g2.y + r.z * g2.z + r.w * g2.w;
        rv[i] = r; cv[i] = c;
    }
#pragma unroll
    for (int off = 32; off > 0; off >>= 1) d += __shfl_xor(d, off);
    d += gb[0];
    const float g = 1.0f / (1.0f + __expf(-d));

    unsigned short* xb = XRb + (size_t)row * 1536;
#pragma unroll
    for (int i = 0; i < 3; ++i) {
        const int c4 = i * 256 + lane * 4;
        ushort4 xo, ro;
        xo.x = f2bf(cv[i].x + g * rv[i].x); xo.y = f2bf(cv[i].y + g * rv[i].y);
        xo.z = f2bf(cv[i].z + g * rv[i].z); xo.w = f2bf(cv[i].w + g * rv[i].w);
        ro.x = f2bf(rv[i].x); ro.y = f2bf(rv[i].y);
        ro.z = f2bf(rv[i].z); ro.w = f2bf(rv[i].w);
        *(ushort4*)&xb[c4] = xo;
        *(ushort4*)&xb[DIM + c4] = ro;
    }
}

// ---------------------------------------------------------------------------
// MFMA GEMM: C[M x 768] = A[M x K](bf16) @ WT[768 x K](bf16, [n][k]) + bias.
// ---------------------------------------------------------------------------
template <int K, int ACT>
__global__ __launch_bounds__(256, 2)
void gemm_mfma(const unsigned short* __restrict__ A, const unsigned short* __restrict__ WT,
               const float* __restrict__ bias, const float* __restrict__ gamma,
               const float* __restrict__ beta, void* __restrict__ outv)
{
    __shared__ __align__(16) unsigned short As[16 * 256];   // 8 KB, xor-swizzled
    __shared__ float red[2][4][16];

    const int tid  = threadIdx.x;
    const int w    = tid >> 6;
    const int lane = tid & 63;
    const int quad = lane >> 4;
    const int l16  = lane & 15;
    const int row0 = blockIdx.x * 16;
    const int nbase = w * 192;
    const int xsw3 = l16 & 7;

    f32x4 acc[12];
#pragma unroll
    for (int nt = 0; nt < 12; ++nt) acc[nt] = (f32x4){0.f, 0.f, 0.f, 0.f};

    bf16x8 b[12];
#pragma unroll
    for (int nt = 0; nt < 12; ++nt)
        b[nt] = *(const bf16x8*)&WT[(size_t)(nbase + nt * 16 + l16) * K + quad * 8];

    for (int ch = 0; ch < K / 256; ++ch) {
        const int kc0 = ch * 256;
        __syncthreads();
#pragma unroll
        for (int i = 0; i < 2; ++i) {
            const int f = tid + i * 256;
            const int r = f >> 5, kb8 = f & 31;
            *(uint4*)&As[r * 256 + ((kb8 ^ (r & 7)) << 3)] =
                *(const uint4*)&A[(size_t)(row0 + r) * K + kc0 + kb8 * 8];
        }
        __syncthreads();
#pragma unroll
        for (int ks = 0; ks < 8; ++ks) {
            const int kc = ks * 32;
            bf16x8 af = *(const bf16x8*)&As[l16 * 256 + ((((kc >> 3) + quad) ^ xsw3) << 3)];
            int gn = kc0 + kc + 32;
            if (gn >= K) gn = 0;                      // dummy wrap (harmless)
#pragma unroll
            for (int nt = 0; nt < 12; ++nt) {
                acc[nt] = __builtin_amdgcn_mfma_f32_16x16x32_bf16(af, b[nt], acc[nt], 0, 0, 0);
                b[nt] = *(const bf16x8*)&WT[(size_t)(nbase + nt * 16 + l16) * K + gn + quad * 8];
            }
        }
    }

    float bv[12];
#pragma unroll
    for (int nt = 0; nt < 12; ++nt) bv[nt] = bias[nbase + nt * 16 + l16];

    if (ACT == 0) {
        unsigned short* out = (unsigned short*)outv;
#pragma unroll
        for (int nt = 0; nt < 12; ++nt)
#pragma unroll
            for (int r = 0; r < 4; ++r) {
                const int row = row0 + quad * 4 + r;
                float v = acc[nt][r] + bv[nt];
                v = 0.5f * v * (1.0f + erff(v * 0.7071067811865476f));
                out[(size_t)row * DIM + nbase + nt * 16 + l16] = f2bf(v);
            }
    } else {
        float* out = (float*)outv;
        float v[12][4];
        float s1[4] = {0.f, 0.f, 0.f, 0.f}, s2[4] = {0.f, 0.f, 0.f, 0.f};
#pragma unroll
        for (int nt = 0; nt < 12; ++nt)
#pragma unroll
            for (int r = 0; r < 4; ++r) {
                float t = acc[nt][r] + bv[nt];
                v[nt][r] = t;
                s1[r] += t;
                s2[r] += t * t;
            }
#pragma unroll
        for (int r = 0; r < 4; ++r) {
#pragma unroll
            for (int off = 1; off < 16; off <<= 1) {
                s1[r] += __shfl_xor(s1[r], off);
                s2[r] += __shfl_xor(s2[r], off);
            }
            if (l16 == 0) {
                red[0][w][quad * 4 + r] = s1[r];
                red[1][w][quad * 4 + r] = s2[r];
            }
        }
        __syncthreads();
#pragma unroll
        for (int r = 0; r < 4; ++r) {
            const int rl16 = quad * 4 + r;
            const float t1 = red[0][0][rl16] + red[0][1][rl16] + red[0][2][rl16] + red[0][3][rl16];
            const float t2 = red[1][0][rl16] + red[1][1][rl16] + red[1][2][rl16] + red[1][3][rl16];
            const float mu  = t1 * (1.0f / 768.0f);
            const float var = fmaxf(t2 * (1.0f / 768.0f) - mu * mu, 0.f);
            const float rs  = rsqrtf(var + 1e-5f);
            const int row = row0 + rl16;
#pragma unroll
            for (int nt = 0; nt < 12; ++nt) {
                const int col = nbase + nt * 16 + l16;
                out[(size_t)row * DIM + col] = (v[nt][r] - mu) * rs * gamma[col] + beta[col];
            }
        }
    }
}

// ---------------------------------------------------------------------------
extern "C" void kernel_launch(void* const* d_in, const int* in_sizes, int n_in,
                              void* d_out, int out_size, void* d_ws, size_t ws_size,
                              hipStream_t stream)
{
    const float* cs  = (const float*)d_in[0];
    const float* mem = (const float*)d_in[1];
    const float* gw  = (const float*)d_in[2];
    const float* gb  = (const float*)d_in[3];
    const float* fw1 = (const float*)d_in[4];
    const float* fb1 = (const float*)d_in[5];
    const float* fw2 = (const float*)d_in[6];
    const float* fb2 = (const float*)d_in[7];
    const float* gam = (const float*)d_in[8];
    const float* bet = (const float*)d_in[9];
    float* out = (float*)d_out;

    char* ws = (char*)d_ws;
    // Layout A (atomic fallback, ~72.8 MB) / Layout B (plain, ~98 MB):
    const size_t PLAIN_WS = 97976320;
    const bool plain = (ws_size >= PLAIN_WS);

    unsigned short* memF = (unsigned short*)ws;                 // 15,728,640
    unsigned short* memS = (unsigned short*)(ws + 15728640);    // 15,728,640
    unsigned short* qH   = (unsigned short*)(ws + 31457280);    // 12,582,912
    float*          retr = (float*)(ws + 44040192);             // A: 25,165,824 / B: 50,331,648
    float*          Lvec;
    unsigned short* w12T;
    unsigned short* w2T;
    if (plain) {
        Lvec = (float*)(ws + 94371840);            // 65,536 (2 splits)
        w12T = (unsigned short*)(ws + 94437376);   // 2,359,296
        w2T  = (unsigned short*)(ws + 96796672);   // 1,179,648 -> end 97,976,320
    } else {
        Lvec = (float*)(ws + 69206016);            // 32,768
        w12T = (unsigned short*)(ws + 69238784);   // 2,359,296
        w2T  = (unsigned short*)(ws + 71598080);   // 1,179,648 -> end 72,777,728
    }
    unsigned short* XRb  = (unsigned short*)ws;                 // alias memF+memS (dead after attn)
    unsigned short* hb   = qH;                                  // alias qH (dead after attn)

    if (!plain)
        hipMemsetAsync(retr, 0, 25165824 + 32768, stream);      // atomic path needs zeroed accum

    cvt_memF<<<MEMP / 16, 256, 0, stream>>>(mem, memF);
    cvt_qH<<<(N_TOK * DIM) / (256 * 4), 256, 0, stream>>>(cs, qH);
    cvt_memS<<<dim3(MEMP / 32, DIM / 64), 256, 0, stream>>>(mem, memS);
    prep_w12T<<<dim3(48, 24), 256, 0, stream>>>(fw1, w12T);
    prep_w2T<<<dim3(24, 24), 256, 0, stream>>>(fw2, w2T);

    if (plain) {
        attn_mfma<1><<<dim3(N_TOK / TQ, NSPLIT), 1024, 0, stream>>>(qH, memF, memS, retr, Lvec);
        finalize_xr<1><<<N_TOK / 4, 256, 0, stream>>>(retr, Lvec, cs, gw, gb, XRb);
    } else {
        attn_mfma<0><<<dim3(N_TOK / TQ, NSPLIT), 1024, 0, stream>>>(qH, memF, memS, retr, Lvec);
        finalize_xr<0><<<N_TOK / 4, 256, 0, stream>>>(retr, Lvec, cs, gw, gb, XRb);
    }
    gemm_mfma<1536, 0><<<N_TOK / 16, 256, 0, stream>>>(XRb, w12T, fb1, nullptr, nullptr, hb);
    gemm_mfma<768, 1><<<N_TOK / 16, 256, 0, stream>>>(hb, w2T, fb2, gam, bet, out);
}

// Round 9
// 937.499 us; speedup vs baseline: 1.1831x; 1.0012x over previous
//
#include <hip/hip_runtime.h>
#include <math.h>

#define N_TOK 8192
#define DIM   768
#define MEMN  10000
#define MEMP  10240            // padded to 40*256
#define TQ    64
#define TM    256
#define NSPLIT 2
#define TILES_PER_SPLIT 20

constexpr float SCALE = 0.036084391824351615f;  // 1/sqrt(768)

typedef short bf16x8 __attribute__((ext_vector_type(8)));
typedef float f32x4  __attribute__((ext_vector_type(4)));

__device__ __forceinline__ unsigned short f2bf(float f) {
    unsigned u = __float_as_uint(f);
    unsigned r = (u + 0x7fffu + ((u >> 16) & 1u)) >> 16;   // RTN-even
    return (unsigned short)r;
}

// ---------------------------------------------------------------------------
// memF: fragment-linear bf16 layout of mem for phase 1 (QK^T B-operand).
// slot(mb, kc, l16, quad, j) = mem[mb*16 + l16][kc*32 + quad*8 + j]
// offset (ushorts) = (mb*24 + kc)*512 + (l16*4 + quad)*8
// ---------------------------------------------------------------------------
__global__ void cvt_memF(const float* __restrict__ mem, unsigned short* __restrict__ dst)
{
    const int mb = blockIdx.x;                       // 0..639
    const bool zero = (mb >= MEMN / 16);             // 625 exact blocks valid
#pragma unroll
    for (int it = 0; it < 6; ++it) {
        const int s   = it * 256 + threadIdx.x;      // 0..1535
        const int kc  = s >> 6;
        const int r   = s & 63;
        const int l16 = r >> 2, q = r & 3;
        unsigned short o[8];
        if (!zero) {
            const float* src = &mem[(size_t)(mb * 16 + l16) * DIM + kc * 32 + q * 8];
            float4 v0 = *(const float4*)src;
            float4 v1 = *(const float4*)(src + 4);
            o[0] = f2bf(v0.x); o[1] = f2bf(v0.y); o[2] = f2bf(v0.z); o[3] = f2bf(v0.w);
            o[4] = f2bf(v1.x); o[5] = f2bf(v1.y); o[6] = f2bf(v1.z); o[7] = f2bf(v1.w);
        } else {
#pragma unroll
            for (int j = 0; j < 8; ++j) o[j] = 0;
        }
        *(uint4*)&dst[((size_t)mb * 24 + kc) * 512 + r * 8] = *(const uint4*)o;
    }
}

// ---------------------------------------------------------------------------
// Q fp32 -> bf16 (row-major, same layout)
// ---------------------------------------------------------------------------
__global__ void cvt_qH(const float* __restrict__ q, unsigned short* __restrict__ dst)
{
    const size_t i = ((size_t)blockIdx.x * 256 + threadIdx.x) * 4;
    float4 v = *(const float4*)&q[i];
    ushort4 o;
    o.x = f2bf(v.x); o.y = f2bf(v.y); o.z = f2bf(v.z); o.w = f2bf(v.w);
    *(ushort4*)&dst[i] = o;
}

// ---------------------------------------------------------------------------
// memS: fragment-linear transposed layout for phase 2 (PV B-operand).
// slot(db, mc, l16, quad, j) = mem[mc*32 + quad*8 + j][db*16 + l16]  (0 if m>=10000)
// offset (ushorts) = (db*320 + mc)*512 + (l16*4 + quad)*8
// ---------------------------------------------------------------------------
__global__ void cvt_memS(const float* __restrict__ mem, unsigned short* __restrict__ dst)
{
    __shared__ float T[32][65];
    const int mc = blockIdx.x;              // m-chunk of 32
    const int d0 = blockIdx.y * 64;         // d base
    const int tx = threadIdx.x & 63;        // d within 64
    const int ty = threadIdx.x >> 6;        // 0..3
#pragma unroll
    for (int i = 0; i < 8; ++i) {
        const int row = ty + 4 * i;                  // 0..31
        const int m   = mc * 32 + row;
        T[row][tx] = (m < MEMN) ? mem[(size_t)m * DIM + d0 + tx] : 0.f;
    }
    __syncthreads();
    const int dbl = threadIdx.x >> 6;       // local 16-d block 0..3
    const int r   = threadIdx.x & 63;
    const int l16 = r >> 2, q = r & 3;
    unsigned short o[8];
#pragma unroll
    for (int j = 0; j < 8; ++j) o[j] = f2bf(T[q * 8 + j][dbl * 16 + l16]);
    *(uint4*)&dst[((size_t)(d0 / 16 + dbl) * 320 + mc) * 512 + r * 8] = *(const uint4*)o;
}

// ---------------------------------------------------------------------------
// W12T fragment-linear: slot(n16, kc, l16, quad, j) = W[n16*16+l16][kc*32+quad*8+j]
// where W[n][k] = w1[768+k][n] (+ w1[k][n] if k<768).  48 n16-blocks x 48 kc.
// offset (ushorts) = (n16*48 + kc)*512 + (l16*4+quad)*8.  grid (48,24), 256 thr.
// ---------------------------------------------------------------------------
__global__ void prep_w12T(const float* __restrict__ w1, unsigned short* __restrict__ wt)
{
    __shared__ float T[32][33];
    const int kb = blockIdx.x * 32, nb = blockIdx.y * 32;
    const int tx = threadIdx.x & 31, ty = threadIdx.x >> 5;
#pragma unroll
    for (int i = 0; i < 4; ++i) {
        int k = kb + ty + 8 * i;
        float v = w1[(size_t)(768 + k) * DIM + nb + tx];
        if (kb < 768) v += w1[(size_t)k * DIM + nb + tx];
        T[ty + 8 * i][tx] = v;              // T[k_local][n_local]
    }
    __syncthreads();
    if (threadIdx.x < 128) {
        const int sub = threadIdx.x >> 6;   // n16 sub-block 0/1 within nb
        const int r   = threadIdx.x & 63;
        const int l16 = r >> 2, q = r & 3;
        unsigned short o[8];
#pragma unroll
        for (int j = 0; j < 8; ++j) o[j] = f2bf(T[q * 8 + j][sub * 16 + l16]);
        const int n16 = (nb >> 4) + sub;
        const int kc  = kb >> 5;
        *(uint4*)&wt[((size_t)n16 * 48 + kc) * 512 + r * 8] = *(const uint4*)o;
    }
}

// ---------------------------------------------------------------------------
// W2T fragment-linear: slot(n16, kc, l16, quad, j) = w2[kc*32+quad*8+j][n16*16+l16]
// 48 n16-blocks x 24 kc.  offset = (n16*24 + kc)*512 + (l16*4+quad)*8.
// grid (24,24), 256 thr.
// ---------------------------------------------------------------------------
__global__ void prep_w2T(const float* __restrict__ w2, unsigned short* __restrict__ wt)
{
    __shared__ float T[32][33];
    const int kb = blockIdx.x * 32, nb = blockIdx.y * 32;
    const int tx = threadIdx.x & 31, ty = threadIdx.x >> 5;
#pragma unroll
    for (int i = 0; i < 4; ++i)
        T[ty + 8 * i][tx] = w2[(size_t)(kb + ty + 8 * i) * DIM + nb + tx];  // T[k_local][n_local]
    __syncthreads();
    if (threadIdx.x < 128) {
        const int sub = threadIdx.x >> 6;
        const int r   = threadIdx.x & 63;
        const int l16 = r >> 2, q = r & 3;
        unsigned short o[8];
#pragma unroll
        for (int j = 0; j < 8; ++j) o[j] = f2bf(T[q * 8 + j][sub * 16 + l16]);
        const int n16 = (nb >> 4) + sub;
        const int kc  = kb >> 5;
        *(uint4*)&wt[((size_t)n16 * 24 + kc) * 512 + r * 8] = *(const uint4*)o;
    }
}

// ---------------------------------------------------------------------------
// Fused MFMA attention. Round-15 structure (VERIFIED 601 us) -- UNCHANGED.
// TQ=64, 16 waves, plain-store epilogue, frag-linear memF/memS.
// Register budget exactly saturated (64 VGPR + 64 AGPR = 128): do not add
// register state here.
// ---------------------------------------------------------------------------
template <int PLAIN>
__global__ __launch_bounds__(1024, 4)
void attn_mfma(const unsigned short* __restrict__ qH, const unsigned short* __restrict__ memF,
               const unsigned short* __restrict__ memS,
               float* __restrict__ retrRaw, float* __restrict__ Lvec)
{
    __shared__ __align__(16) unsigned short Qs[64 * 768];   // 96 KB, xor-swizzled
    __shared__ __align__(16) unsigned short Ps[64 * 256];   // 32 KB, xor-swizzled
    __shared__ float Lred[16][64];                          // 4 KB, L block-reduce

    const int tid    = threadIdx.x;
    const int w      = tid >> 6;         // wave 0..15
    const int lane   = tid & 63;
    const int quad   = lane >> 4;        // 0..3
    const int l16    = lane & 15;
    const int fr     = ((l16 << 2) | quad) << 3;   // fragment-linear lane offset (ushorts)

    const int split = blockIdx.y;
    const int q0    = blockIdx.x * TQ;   // 0..8128 step 64

    const int dbase  = w * 48;           // phase-2 d-strip per wave (3 x 16)
    const int mstrip = w * 16;           // phase-1 m-strip per wave (1 x 16)

    // ---- stage Q tile (64 rows, bf16, swizzled) once ----
    {
        const int qr  = tid >> 4;            // 0..63
        const int db0 = tid & 15;
        const unsigned short* src = qH + (size_t)(q0 + qr) * DIM;
        const int sw = qr & 7;
#pragma unroll
        for (int i = 0; i < 6; ++i) {
            int db = db0 + i * 16;           // 0..95 (blocks of 8 bf16)
            uint4 v = *(const uint4*)&src[db * 8];
            *(uint4*)&Qs[qr * 768 + ((db ^ sw) << 3)] = v;
        }
    }
    __syncthreads();

    f32x4 oacc[4][3];
#pragma unroll
    for (int a = 0; a < 4; ++a)
#pragma unroll
        for (int b = 0; b < 3; ++b) oacc[a][b] = (f32x4){0.f, 0.f, 0.f, 0.f};
    float lsum[4][4];
#pragma unroll
    for (int a = 0; a < 4; ++a)
#pragma unroll
        for (int r = 0; r < 4; ++r) lsum[a][r] = 0.f;

    const int xsw = l16 & 7;   // rows l16,16+l16,32+l16,48+l16 share (row&7)

    for (int st = 0; st < TILES_PER_SPLIT; ++st) {
        const int m0  = (split * TILES_PER_SPLIT + st) * TM;
        const int mc0 = m0 >> 5;                          // m-chunk base for phase 2

        // ---- phase 1: S[64 x 256]; wave w covers m-strip mstrip..+16 ----
        f32x4 sacc[4];
#pragma unroll
        for (int a = 0; a < 4; ++a) sacc[a] = (f32x4){0.f, 0.f, 0.f, 0.f};

        const unsigned short* fb = memF + ((size_t)(m0 >> 4) + w) * 12288 + fr;

        bf16x8 pb[2];
        pb[0] = *(const bf16x8*)(fb);
        pb[1] = *(const bf16x8*)(fb + 512);

#pragma unroll
        for (int ks = 0; ks < 24; ++ks) {
            const int xq = (((ks << 2) + quad) ^ xsw) << 3;
            bf16x8 a0 = *(const bf16x8*)&Qs[l16 * 768 + xq];
            bf16x8 a1 = *(const bf16x8*)&Qs[(16 + l16) * 768 + xq];
            bf16x8 a2 = *(const bf16x8*)&Qs[(32 + l16) * 768 + xq];
            bf16x8 a3 = *(const bf16x8*)&Qs[(48 + l16) * 768 + xq];
            bf16x8 b = pb[ks & 1];
            sacc[0] = __builtin_amdgcn_mfma_f32_16x16x32_bf16(a0, b, sacc[0], 0, 0, 0);
            sacc[1] = __builtin_amdgcn_mfma_f32_16x16x32_bf16(a1, b, sacc[1], 0, 0, 0);
            sacc[2] = __builtin_amdgcn_mfma_f32_16x16x32_bf16(a2, b, sacc[2], 0, 0, 0);
            sacc[3] = __builtin_amdgcn_mfma_f32_16x16x32_bf16(a3, b, sacc[3], 0, 0, 0);
            if (ks < 22) pb[ks & 1] = *(const bf16x8*)(fb + (ks + 2) * 512);
        }

        __syncthreads();   // barrier A: all waves done reading previous tile's Ps

        // ---- exp + P->LDS (bf16, swizzled) + row-sum accumulation ----
        {
            const int mloc = mstrip + l16;               // 0..255
            const bool ok  = (m0 + mloc) < MEMN;
#pragma unroll
            for (int qt = 0; qt < 4; ++qt)
#pragma unroll
                for (int r = 0; r < 4; ++r) {
                    float p = ok ? __expf(sacc[qt][r] * SCALE) : 0.f;
                    const int q = qt * 16 + quad * 4 + r;     // 0..63
                    lsum[qt][r] += p;
                    Ps[q * 256 + (((mloc >> 3) ^ (q & 7)) << 3) + (mloc & 7)] = f2bf(p);
                }
        }

        __syncthreads();   // barrier B: Ps complete

        // ---- phase 2: O += P * Mem; depth-2 register prefetch of B-frags ----
        const unsigned short* msp = memS + ((size_t)(3 * w) * 320 + mc0) * 512 + fr;
        bf16x8 cb[2][3];
#pragma unroll
        for (int nt = 0; nt < 3; ++nt) {
            cb[0][nt] = *(const bf16x8*)(msp + (size_t)nt * 163840);
            cb[1][nt] = *(const bf16x8*)(msp + (size_t)nt * 163840 + 512);
        }

#pragma unroll
        for (int ks = 0; ks < 8; ++ks) {
            const int xp = (((ks << 2) + quad) ^ xsw) << 3;
            bf16x8 pa0 = *(const bf16x8*)&Ps[l16 * 256 + xp];
            bf16x8 pa1 = *(const bf16x8*)&Ps[(16 + l16) * 256 + xp];
            bf16x8 pa2 = *(const bf16x8*)&Ps[(32 + l16) * 256 + xp];
            bf16x8 pa3 = *(const bf16x8*)&Ps[(48 + l16) * 256 + xp];
            const bool dopf = (ks < 6);
#pragma unroll
            for (int nt = 0; nt < 3; ++nt) {
                oacc[0][nt] = __builtin_amdgcn_mfma_f32_16x16x32_bf16(pa0, cb[ks & 1][nt], oacc[0][nt], 0, 0, 0);
                oacc[1][nt] = __builtin_amdgcn_mfma_f32_16x16x32_bf16(pa1, cb[ks & 1][nt], oacc[1][nt], 0, 0, 0);
                oacc[2][nt] = __builtin_amdgcn_mfma_f32_16x16x32_bf16(pa2, cb[ks & 1][nt], oacc[2][nt], 0, 0, 0);
                oacc[3][nt] = __builtin_amdgcn_mfma_f32_16x16x32_bf16(pa3, cb[ks & 1][nt], oacc[3][nt], 0, 0, 0);
                if (dopf) cb[ks & 1][nt] = *(const bf16x8*)(msp + (size_t)nt * 163840 + (ks + 2) * 512);
            }
        }
    }

    // ---- epilogue: combine O and L across splits ----
    float* ob = retrRaw + (PLAIN ? (size_t)split * ((size_t)N_TOK * DIM) : (size_t)0);
#pragma unroll
    for (int qt = 0; qt < 4; ++qt)
#pragma unroll
        for (int nt = 0; nt < 3; ++nt)
#pragma unroll
            for (int r = 0; r < 4; ++r) {
                const size_t idx = (size_t)(q0 + qt * 16 + quad * 4 + r) * DIM + dbase + nt * 16 + l16;
                if (PLAIN)
                    ob[idx] = oacc[qt][nt][r];
                else
                    __hip_atomic_fetch_add(&ob[idx], oacc[qt][nt][r],
                                           __ATOMIC_RELAXED, __HIP_MEMORY_SCOPE_AGENT);
            }

#pragma unroll
    for (int qt = 0; qt < 4; ++qt)
#pragma unroll
        for (int r = 0; r < 4; ++r) {
            float v = lsum[qt][r];
#pragma unroll
            for (int off = 1; off < 16; off <<= 1) v += __shfl_xor(v, off);
            if (l16 == 0) {
                if (PLAIN)
                    Lred[w][qt * 16 + quad * 4 + r] = v;
                else
                    __hip_atomic_fetch_add(&Lvec[q0 + qt * 16 + quad * 4 + r], v,
                                           __ATOMIC_RELAXED, __HIP_MEMORY_SCOPE_AGENT);
            }
        }
    if (PLAIN) {
        __syncthreads();
        if (tid < 64) {
            float s = 0.f;
#pragma unroll
            for (int ww = 0; ww < 16; ++ww) s += Lred[ww][tid];
            Lvec[(size_t)split * N_TOK + q0 + tid] = s;
        }
    }
}

// ---------------------------------------------------------------------------
// Normalize retrieved, compute gate, build XRb = bf16([cs + g*r | r]).
// PLAIN=1: retrRaw/Lvec hold 2 split-partials, summed here.
// ---------------------------------------------------------------------------
template <int PLAIN>
__global__ __launch_bounds__(256)
void finalize_xr(const float* __restrict__ retrRaw, const float* __restrict__ Lvec,
                 const float* __restrict__ cs, const float* __restrict__ gw,
                 const float* __restrict__ gb, unsigned short* __restrict__ XRb)
{
    const int lane = threadIdx.x & 63;
    const int row  = blockIdx.x * 4 + (threadIdx.x >> 6);
    const float lv = PLAIN ? (Lvec[row] + Lvec[N_TOK + row]) : Lvec[row];
    const float rl = 1.0f / lv;
    const float* rr  = retrRaw + (size_t)row * DIM;
    const float* rr1 = retrRaw + (size_t)N_TOK * DIM + (size_t)row * DIM;
    const float* cr = cs + (size_t)row * DIM;

    float4 rv[3], cv[3];
    float d = 0.f;
#pragma unroll
    for (int i = 0; i < 3; ++i) {
        const int c4 = i * 256 + lane * 4;
        float4 r = *(const float4*)&rr[c4];
        if (PLAIN) {
            float4 r1 = *(const float4*)&rr1[c4];
            r.x += r1.x; r.y += r1.y; r.z += r1.z; r.w += r1.w;
        }
        r.x *= rl; r.y *= rl; r.z *= rl; r.w *= rl;
        float4 c = *(const float4*)&cr[c4];
        float4 g1 = *(const float4*)&gw[c4];
        float4 g2 = *(const float4*)&gw[DIM + c4];
        d += c.x * g1.x + c.y * g1.y + c.z * g1.z + c.w * g1.w;
        d += r.x * g2.x + r.y * g2.y + r.z * g2.z + r.w * g2.w;
        rv[i] = r; cv[i] = c;
    }
#pragma unroll
    for (int off = 32; off > 0; off >>= 1) d += __shfl_xor(d, off);
    d += gb[0];
    const float g = 1.0f / (1.0f + __expf(-d));

    unsigned short* xb = XRb + (size_t)row * 1536;
#pragma unroll
    for (int i = 0; i < 3; ++i) {
        const int c4 = i * 256 + lane * 4;
        ushort4 xo, ro;
        xo.x = f2bf(cv[i].x + g * rv[i].x); xo.y = f2bf(cv[i].y + g * rv[i].y);
        xo.z = f2bf(cv[i].z + g * rv[i].z); xo.w = f2bf(cv[i].w + g * rv[i].w);
        ro.x = f2bf(rv[i].x); ro.y = f2bf(rv[i].y);
        ro.z = f2bf(rv[i].z); ro.w = f2bf(rv[i].w);
        *(ushort4*)&xb[c4] = xo;
        *(ushort4*)&xb[DIM + c4] = ro;
    }
}

// ---------------------------------------------------------------------------
// MFMA GEMM: C[M x 768] = A[M x K](bf16) @ W(frag-linear) + bias.
// Round-16: W in fragment-linear layout -> every b[nt] load is one contiguous
// 1 KB wave-load (8 full 128B lines) instead of 16 half-used lines at
// stride K.  Register structure unchanged.
// ---------------------------------------------------------------------------
template <int K, int ACT>
__global__ __launch_bounds__(256, 2)
void gemm_mfma(const unsigned short* __restrict__ A, const unsigned short* __restrict__ WT,
               const float* __restrict__ bias, const float* __restrict__ gamma,
               const float* __restrict__ beta, void* __restrict__ outv)
{
    __shared__ __align__(16) unsigned short As[16 * 256];   // 8 KB, xor-swizzled
    __shared__ float red[2][4][16];

    const int tid  = threadIdx.x;
    const int w    = tid >> 6;
    const int lane = tid & 63;
    const int quad = lane >> 4;
    const int l16  = lane & 15;
    const int row0 = blockIdx.x * 16;
    const int nbase = w * 192;
    const int xsw3 = l16 & 7;
    const int KC   = K / 32;                       // k-chunks of 32
    const int fr   = ((l16 << 2) | quad) << 3;     // fragment-linear lane offset
    const int nb16 = w * 12;                       // first n16-block of this wave

    f32x4 acc[12];
#pragma unroll
    for (int nt = 0; nt < 12; ++nt) acc[nt] = (f32x4){0.f, 0.f, 0.f, 0.f};

    bf16x8 b[12];
#pragma unroll
    for (int nt = 0; nt < 12; ++nt)
        b[nt] = *(const bf16x8*)&WT[(size_t)(nb16 + nt) * KC * 512 + fr];

    for (int ch = 0; ch < K / 256; ++ch) {
        const int kc0 = ch * 256;
        __syncthreads();
#pragma unroll
        for (int i = 0; i < 2; ++i) {
            const int f = tid + i * 256;
            const int r = f >> 5, kb8 = f & 31;
            *(uint4*)&As[r * 256 + ((kb8 ^ (r & 7)) << 3)] =
                *(const uint4*)&A[(size_t)(row0 + r) * K + kc0 + kb8 * 8];
        }
        __syncthreads();
#pragma unroll
        for (int ks = 0; ks < 8; ++ks) {
            const int kc = ks * 32;
            bf16x8 af = *(const bf16x8*)&As[l16 * 256 + ((((kc >> 3) + quad) ^ xsw3) << 3)];
            int kn = ch * 8 + ks + 1;             // next global k-chunk index
            if (kn >= KC) kn = 0;                 // dummy wrap (harmless)
#pragma unroll
            for (int nt = 0; nt < 12; ++nt) {
                acc[nt] = __builtin_amdgcn_mfma_f32_16x16x32_bf16(af, b[nt], acc[nt], 0, 0, 0);
                b[nt] = *(const bf16x8*)&WT[((size_t)(nb16 + nt) * KC + kn) * 512 + fr];
            }
        }
    }

    float bv[12];
#pragma unroll
    for (int nt = 0; nt < 12; ++nt) bv[nt] = bias[nbase + nt * 16 + l16];

    if (ACT == 0) {
        unsigned short* out = (unsigned short*)outv;
#pragma unroll
        for (int nt = 0; nt < 12; ++nt)
#pragma unroll
            for (int r = 0; r < 4; ++r) {
                const int row = row0 + quad * 4 + r;
                float v = acc[nt][r] + bv[nt];
                v = 0.5f * v * (1.0f + erff(v * 0.7071067811865476f));
                out[(size_t)row * DIM + nbase + nt * 16 + l16] = f2bf(v);
            }
    } else {
        float* out = (float*)outv;
        float v[12][4];
        float s1[4] = {0.f, 0.f, 0.f, 0.f}, s2[4] = {0.f, 0.f, 0.f, 0.f};
#pragma unroll
        for (int nt = 0; nt < 12; ++nt)
#pragma unroll
            for (int r = 0; r < 4; ++r) {
                float t = acc[nt][r] + bv[nt];
                v[nt][r] = t;
                s1[r] += t;
                s2[r] += t * t;
            }
#pragma unroll
        for (int r = 0; r < 4; ++r) {
#pragma unroll
            for (int off = 1; off < 16; off <<= 1) {
                s1[r] += __shfl_xor(s1[r], off);
                s2[r] += __shfl_xor(s2[r], off);
            }
            if (l16 == 0) {
                red[0][w][quad * 4 + r] = s1[r];
                red[1][w][quad * 4 + r] = s2[r];
            }
        }
        __syncthreads();
#pragma unroll
        for (int r = 0; r < 4; ++r) {
            const int rl16 = quad * 4 + r;
            const float t1 = red[0][0][rl16] + red[0][1][rl16] + red[0][2][rl16] + red[0][3][rl16];
            const float t2 = red[1][0][rl16] + red[1][1][rl16] + red[1][2][rl16] + red[1][3][rl16];
            const float mu  = t1 * (1.0f / 768.0f);
            const float var = fmaxf(t2 * (1.0f / 768.0f) - mu * mu, 0.f);
            const float rs  = rsqrtf(var + 1e-5f);
            const int row = row0 + rl16;
#pragma unroll
            for (int nt = 0; nt < 12; ++nt) {
                const int col = nbase + nt * 16 + l16;
                out[(size_t)row * DIM + col] = (v[nt][r] - mu) * rs * gamma[col] + beta[col];
            }
        }
    }
}

// ---------------------------------------------------------------------------
extern "C" void kernel_launch(void* const* d_in, const int* in_sizes, int n_in,
                              void* d_out, int out_size, void* d_ws, size_t ws_size,
                              hipStream_t stream)
{
    const float* cs  = (const float*)d_in[0];
    const float* mem = (const float*)d_in[1];
    const float* gw  = (const float*)d_in[2];
    const float* gb  = (const float*)d_in[3];
    const float* fw1 = (const float*)d_in[4];
    const float* fb1 = (const float*)d_in[5];
    const float* fw2 = (const float*)d_in[6];
    const float* fb2 = (const float*)d_in[7];
    const float* gam = (const float*)d_in[8];
    const float* bet = (const float*)d_in[9];
    float* out = (float*)d_out;

    char* ws = (char*)d_ws;
    // Layout A (atomic fallback, ~72.8 MB) / Layout B (plain, ~98 MB):
    const size_t PLAIN_WS = 97976320;
    const bool plain = (ws_size >= PLAIN_WS);

    unsigned short* memF = (unsigned short*)ws;                 // 15,728,640
    unsigned short* memS = (unsigned short*)(ws + 15728640);    // 15,728,640
    unsigned short* qH   = (unsigned short*)(ws + 31457280);    // 12,582,912
    float*          retr = (float*)(ws + 44040192);             // A: 25,165,824 / B: 50,331,648
    float*          Lvec;
    unsigned short* w12T;
    unsigned short* w2T;
    if (plain) {
        Lvec = (float*)(ws + 94371840);            // 65,536 (2 splits)
        w12T = (unsigned short*)(ws + 94437376);   // 2,359,296
        w2T  = (unsigned short*)(ws + 96796672);   // 1,179,648 -> end 97,976,320
    } else {
        Lvec = (float*)(ws + 69206016);            // 32,768
        w12T = (unsigned short*)(ws + 69238784);   // 2,359,296
        w2T  = (unsigned short*)(ws + 71598080);   // 1,179,648 -> end 72,777,728
    }
    unsigned short* XRb  = (unsigned short*)ws;                 // alias memF+memS (dead after attn)
    unsigned short* hb   = qH;                                  // alias qH (dead after attn)

    if (!plain)
        hipMemsetAsync(retr, 0, 25165824 + 32768, stream);      // atomic path needs zeroed accum

    cvt_memF<<<MEMP / 16, 256, 0, stream>>>(mem, memF);
    cvt_qH<<<(N_TOK * DIM) / (256 * 4), 256, 0, stream>>>(cs, qH);
    cvt_memS<<<dim3(MEMP / 32, DIM / 64), 256, 0, stream>>>(mem, memS);
    prep_w12T<<<dim3(48, 24), 256, 0, stream>>>(fw1, w12T);
    prep_w2T<<<dim3(24, 24), 256, 0, stream>>>(fw2, w2T);

    if (plain) {
        attn_mfma<1><<<dim3(N_TOK / TQ, NSPLIT), 1024, 0, stream>>>(qH, memF, memS, retr, Lvec);
        finalize_xr<1><<<N_TOK / 4, 256, 0, stream>>>(retr, Lvec, cs, gw, gb, XRb);
    } else {
        attn_mfma<0><<<dim3(N_TOK / TQ, NSPLIT), 1024, 0, stream>>>(qH, memF, memS, retr, Lvec);
        finalize_xr<0><<<N_TOK / 4, 256, 0, stream>>>(retr, Lvec, cs, gw, gb, XRb);
    }
    gemm_mfma<1536, 0><<<N_TOK / 16, 256, 0, stream>>>(XRb, w12T, fb1, nullptr, nullptr, hb);
    gemm_mfma<768, 1><<<N_TOK / 16, 256, 0, stream>>>(hb, w2T, fb2, gam, bet, out);
}

// Round 10
// 838.736 us; speedup vs baseline: 1.3224x; 1.1178x over previous
//
#include <hip/hip_runtime.h>
#include <math.h>

#define N_TOK 8192
#define DIM   768
#define MEMN  10000
#define MEMP  10240            // padded to 40*256
#define TQ    64
#define TM    256
#define NSPLIT 2
#define TILES_PER_SPLIT 20

constexpr float SCALE = 0.036084391824351615f;  // 1/sqrt(768)

typedef short bf16x8 __attribute__((ext_vector_type(8)));
typedef float f32x4  __attribute__((ext_vector_type(4)));

__device__ __forceinline__ unsigned short f2bf(float f) {
    unsigned u = __float_as_uint(f);
    unsigned r = (u + 0x7fffu + ((u >> 16) & 1u)) >> 16;   // RTN-even
    return (unsigned short)r;
}

// ---------------------------------------------------------------------------
// memF: fragment-linear bf16 layout of mem for phase 1 (QK^T B-operand).
// slot(mb, kc, l16, quad, j) = mem[mb*16 + l16][kc*32 + quad*8 + j]
// offset (ushorts) = (mb*24 + kc)*512 + (l16*4 + quad)*8
// ---------------------------------------------------------------------------
__global__ void cvt_memF(const float* __restrict__ mem, unsigned short* __restrict__ dst)
{
    const int mb = blockIdx.x;                       // 0..639
    const bool zero = (mb >= MEMN / 16);             // 625 exact blocks valid
#pragma unroll
    for (int it = 0; it < 6; ++it) {
        const int s   = it * 256 + threadIdx.x;      // 0..1535
        const int kc  = s >> 6;
        const int r   = s & 63;
        const int l16 = r >> 2, q = r & 3;
        unsigned short o[8];
        if (!zero) {
            const float* src = &mem[(size_t)(mb * 16 + l16) * DIM + kc * 32 + q * 8];
            float4 v0 = *(const float4*)src;
            float4 v1 = *(const float4*)(src + 4);
            o[0] = f2bf(v0.x); o[1] = f2bf(v0.y); o[2] = f2bf(v0.z); o[3] = f2bf(v0.w);
            o[4] = f2bf(v1.x); o[5] = f2bf(v1.y); o[6] = f2bf(v1.z); o[7] = f2bf(v1.w);
        } else {
#pragma unroll
            for (int j = 0; j < 8; ++j) o[j] = 0;
        }
        *(uint4*)&dst[((size_t)mb * 24 + kc) * 512 + r * 8] = *(const uint4*)o;
    }
}

// ---------------------------------------------------------------------------
// Q fp32 -> bf16 (row-major, same layout)
// ---------------------------------------------------------------------------
__global__ void cvt_qH(const float* __restrict__ q, unsigned short* __restrict__ dst)
{
    const size_t i = ((size_t)blockIdx.x * 256 + threadIdx.x) * 4;
    float4 v = *(const float4*)&q[i];
    ushort4 o;
    o.x = f2bf(v.x); o.y = f2bf(v.y); o.z = f2bf(v.z); o.w = f2bf(v.w);
    *(ushort4*)&dst[i] = o;
}

// ---------------------------------------------------------------------------
// memS: fragment-linear transposed layout for phase 2 (PV B-operand).
// slot(db, mc, l16, quad, j) = mem[mc*32 + quad*8 + j][db*16 + l16]  (0 if m>=10000)
// ---------------------------------------------------------------------------
__global__ void cvt_memS(const float* __restrict__ mem, unsigned short* __restrict__ dst)
{
    __shared__ float T[32][65];
    const int mc = blockIdx.x;              // m-chunk of 32
    const int d0 = blockIdx.y * 64;         // d base
    const int tx = threadIdx.x & 63;        // d within 64
    const int ty = threadIdx.x >> 6;        // 0..3
#pragma unroll
    for (int i = 0; i < 8; ++i) {
        const int row = ty + 4 * i;                  // 0..31
        const int m   = mc * 32 + row;
        T[row][tx] = (m < MEMN) ? mem[(size_t)m * DIM + d0 + tx] : 0.f;
    }
    __syncthreads();
    const int dbl = threadIdx.x >> 6;       // local 16-d block 0..3
    const int r   = threadIdx.x & 63;
    const int l16 = r >> 2, q = r & 3;
    unsigned short o[8];
#pragma unroll
    for (int j = 0; j < 8; ++j) o[j] = f2bf(T[q * 8 + j][dbl * 16 + l16]);
    *(uint4*)&dst[((size_t)(d0 / 16 + dbl) * 320 + mc) * 512 + r * 8] = *(const uint4*)o;
}

// ---------------------------------------------------------------------------
// W12T fragment-linear: slot(n16, kc, l16, quad, j) = W[n16*16+l16][kc*32+quad*8+j]
// where W[n][k] = w1[768+k][n] (+ w1[k][n] if k<768).  48 n16-blocks x 48 kc.
// ---------------------------------------------------------------------------
__global__ void prep_w12T(const float* __restrict__ w1, unsigned short* __restrict__ wt)
{
    __shared__ float T[32][33];
    const int kb = blockIdx.x * 32, nb = blockIdx.y * 32;
    const int tx = threadIdx.x & 31, ty = threadIdx.x >> 5;
#pragma unroll
    for (int i = 0; i < 4; ++i) {
        int k = kb + ty + 8 * i;
        float v = w1[(size_t)(768 + k) * DIM + nb + tx];
        if (kb < 768) v += w1[(size_t)k * DIM + nb + tx];
        T[ty + 8 * i][tx] = v;              // T[k_local][n_local]
    }
    __syncthreads();
    if (threadIdx.x < 128) {
        const int sub = threadIdx.x >> 6;   // n16 sub-block 0/1 within nb
        const int r   = threadIdx.x & 63;
        const int l16 = r >> 2, q = r & 3;
        unsigned short o[8];
#pragma unroll
        for (int j = 0; j < 8; ++j) o[j] = f2bf(T[q * 8 + j][sub * 16 + l16]);
        const int n16 = (nb >> 4) + sub;
        const int kc  = kb >> 5;
        *(uint4*)&wt[((size_t)n16 * 48 + kc) * 512 + r * 8] = *(const uint4*)o;
    }
}

// ---------------------------------------------------------------------------
// W2T fragment-linear: slot(n16, kc, l16, quad, j) = w2[kc*32+quad*8+j][n16*16+l16]
// 48 n16-blocks x 24 kc.
// ---------------------------------------------------------------------------
__global__ void prep_w2T(const float* __restrict__ w2, unsigned short* __restrict__ wt)
{
    __shared__ float T[32][33];
    const int kb = blockIdx.x * 32, nb = blockIdx.y * 32;
    const int tx = threadIdx.x & 31, ty = threadIdx.x >> 5;
#pragma unroll
    for (int i = 0; i < 4; ++i)
        T[ty + 8 * i][tx] = w2[(size_t)(kb + ty + 8 * i) * DIM + nb + tx];  // T[k_local][n_local]
    __syncthreads();
    if (threadIdx.x < 128) {
        const int sub = threadIdx.x >> 6;
        const int r   = threadIdx.x & 63;
        const int l16 = r >> 2, q = r & 3;
        unsigned short o[8];
#pragma unroll
        for (int j = 0; j < 8; ++j) o[j] = f2bf(T[q * 8 + j][sub * 16 + l16]);
        const int n16 = (nb >> 4) + sub;
        const int kc  = kb >> 5;
        *(uint4*)&wt[((size_t)n16 * 24 + kc) * 512 + r * 8] = *(const uint4*)o;
    }
}

// ---------------------------------------------------------------------------
// Fused MFMA attention. Round-15 structure (VERIFIED 599-601 us) -- UNCHANGED.
// ---------------------------------------------------------------------------
template <int PLAIN>
__global__ __launch_bounds__(1024, 4)
void attn_mfma(const unsigned short* __restrict__ qH, const unsigned short* __restrict__ memF,
               const unsigned short* __restrict__ memS,
               float* __restrict__ retrRaw, float* __restrict__ Lvec)
{
    __shared__ __align__(16) unsigned short Qs[64 * 768];   // 96 KB, xor-swizzled
    __shared__ __align__(16) unsigned short Ps[64 * 256];   // 32 KB, xor-swizzled
    __shared__ float Lred[16][64];                          // 4 KB, L block-reduce

    const int tid    = threadIdx.x;
    const int w      = tid >> 6;         // wave 0..15
    const int lane   = tid & 63;
    const int quad   = lane >> 4;        // 0..3
    const int l16    = lane & 15;
    const int fr     = ((l16 << 2) | quad) << 3;   // fragment-linear lane offset (ushorts)

    const int split = blockIdx.y;
    const int q0    = blockIdx.x * TQ;   // 0..8128 step 64

    const int dbase  = w * 48;           // phase-2 d-strip per wave (3 x 16)
    const int mstrip = w * 16;           // phase-1 m-strip per wave (1 x 16)

    // ---- stage Q tile (64 rows, bf16, swizzled) once ----
    {
        const int qr  = tid >> 4;            // 0..63
        const int db0 = tid & 15;
        const unsigned short* src = qH + (size_t)(q0 + qr) * DIM;
        const int sw = qr & 7;
#pragma unroll
        for (int i = 0; i < 6; ++i) {
            int db = db0 + i * 16;           // 0..95 (blocks of 8 bf16)
            uint4 v = *(const uint4*)&src[db * 8];
            *(uint4*)&Qs[qr * 768 + ((db ^ sw) << 3)] = v;
        }
    }
    __syncthreads();

    f32x4 oacc[4][3];
#pragma unroll
    for (int a = 0; a < 4; ++a)
#pragma unroll
        for (int b = 0; b < 3; ++b) oacc[a][b] = (f32x4){0.f, 0.f, 0.f, 0.f};
    float lsum[4][4];
#pragma unroll
    for (int a = 0; a < 4; ++a)
#pragma unroll
        for (int r = 0; r < 4; ++r) lsum[a][r] = 0.f;

    const int xsw = l16 & 7;

    for (int st = 0; st < TILES_PER_SPLIT; ++st) {
        const int m0  = (split * TILES_PER_SPLIT + st) * TM;
        const int mc0 = m0 >> 5;

        // ---- phase 1: S[64 x 256]; wave w covers m-strip mstrip..+16 ----
        f32x4 sacc[4];
#pragma unroll
        for (int a = 0; a < 4; ++a) sacc[a] = (f32x4){0.f, 0.f, 0.f, 0.f};

        const unsigned short* fb = memF + ((size_t)(m0 >> 4) + w) * 12288 + fr;

        bf16x8 pb[2];
        pb[0] = *(const bf16x8*)(fb);
        pb[1] = *(const bf16x8*)(fb + 512);

#pragma unroll
        for (int ks = 0; ks < 24; ++ks) {
            const int xq = (((ks << 2) + quad) ^ xsw) << 3;
            bf16x8 a0 = *(const bf16x8*)&Qs[l16 * 768 + xq];
            bf16x8 a1 = *(const bf16x8*)&Qs[(16 + l16) * 768 + xq];
            bf16x8 a2 = *(const bf16x8*)&Qs[(32 + l16) * 768 + xq];
            bf16x8 a3 = *(const bf16x8*)&Qs[(48 + l16) * 768 + xq];
            bf16x8 b = pb[ks & 1];
            sacc[0] = __builtin_amdgcn_mfma_f32_16x16x32_bf16(a0, b, sacc[0], 0, 0, 0);
            sacc[1] = __builtin_amdgcn_mfma_f32_16x16x32_bf16(a1, b, sacc[1], 0, 0, 0);
            sacc[2] = __builtin_amdgcn_mfma_f32_16x16x32_bf16(a2, b, sacc[2], 0, 0, 0);
            sacc[3] = __builtin_amdgcn_mfma_f32_16x16x32_bf16(a3, b, sacc[3], 0, 0, 0);
            if (ks < 22) pb[ks & 1] = *(const bf16x8*)(fb + (ks + 2) * 512);
        }

        __syncthreads();   // barrier A

        // ---- exp + P->LDS (bf16, swizzled) + row-sum accumulation ----
        {
            const int mloc = mstrip + l16;               // 0..255
            const bool ok  = (m0 + mloc) < MEMN;
#pragma unroll
            for (int qt = 0; qt < 4; ++qt)
#pragma unroll
                for (int r = 0; r < 4; ++r) {
                    float p = ok ? __expf(sacc[qt][r] * SCALE) : 0.f;
                    const int q = qt * 16 + quad * 4 + r;     // 0..63
                    lsum[qt][r] += p;
                    Ps[q * 256 + (((mloc >> 3) ^ (q & 7)) << 3) + (mloc & 7)] = f2bf(p);
                }
        }

        __syncthreads();   // barrier B

        // ---- phase 2: O += P * Mem; depth-2 register prefetch of B-frags ----
        const unsigned short* msp = memS + ((size_t)(3 * w) * 320 + mc0) * 512 + fr;
        bf16x8 cb[2][3];
#pragma unroll
        for (int nt = 0; nt < 3; ++nt) {
            cb[0][nt] = *(const bf16x8*)(msp + (size_t)nt * 163840);
            cb[1][nt] = *(const bf16x8*)(msp + (size_t)nt * 163840 + 512);
        }

#pragma unroll
        for (int ks = 0; ks < 8; ++ks) {
            const int xp = (((ks << 2) + quad) ^ xsw) << 3;
            bf16x8 pa0 = *(const bf16x8*)&Ps[l16 * 256 + xp];
            bf16x8 pa1 = *(const bf16x8*)&Ps[(16 + l16) * 256 + xp];
            bf16x8 pa2 = *(const bf16x8*)&Ps[(32 + l16) * 256 + xp];
            bf16x8 pa3 = *(const bf16x8*)&Ps[(48 + l16) * 256 + xp];
            const bool dopf = (ks < 6);
#pragma unroll
            for (int nt = 0; nt < 3; ++nt) {
                oacc[0][nt] = __builtin_amdgcn_mfma_f32_16x16x32_bf16(pa0, cb[ks & 1][nt], oacc[0][nt], 0, 0, 0);
                oacc[1][nt] = __builtin_amdgcn_mfma_f32_16x16x32_bf16(pa1, cb[ks & 1][nt], oacc[1][nt], 0, 0, 0);
                oacc[2][nt] = __builtin_amdgcn_mfma_f32_16x16x32_bf16(pa2, cb[ks & 1][nt], oacc[2][nt], 0, 0, 0);
                oacc[3][nt] = __builtin_amdgcn_mfma_f32_16x16x32_bf16(pa3, cb[ks & 1][nt], oacc[3][nt], 0, 0, 0);
                if (dopf) cb[ks & 1][nt] = *(const bf16x8*)(msp + (size_t)nt * 163840 + (ks + 2) * 512);
            }
        }
    }

    // ---- epilogue: combine O and L across splits ----
    float* ob = retrRaw + (PLAIN ? (size_t)split * ((size_t)N_TOK * DIM) : (size_t)0);
#pragma unroll
    for (int qt = 0; qt < 4; ++qt)
#pragma unroll
        for (int nt = 0; nt < 3; ++nt)
#pragma unroll
            for (int r = 0; r < 4; ++r) {
                const size_t idx = (size_t)(q0 + qt * 16 + quad * 4 + r) * DIM + dbase + nt * 16 + l16;
                if (PLAIN)
                    ob[idx] = oacc[qt][nt][r];
                else
                    __hip_atomic_fetch_add(&ob[idx], oacc[qt][nt][r],
                                           __ATOMIC_RELAXED, __HIP_MEMORY_SCOPE_AGENT);
            }

#pragma unroll
    for (int qt = 0; qt < 4; ++qt)
#pragma unroll
        for (int r = 0; r < 4; ++r) {
            float v = lsum[qt][r];
#pragma unroll
            for (int off = 1; off < 16; off <<= 1) v += __shfl_xor(v, off);
            if (l16 == 0) {
                if (PLAIN)
                    Lred[w][qt * 16 + quad * 4 + r] = v;
                else
                    __hip_atomic_fetch_add(&Lvec[q0 + qt * 16 + quad * 4 + r], v,
                                           __ATOMIC_RELAXED, __HIP_MEMORY_SCOPE_AGENT);
            }
        }
    if (PLAIN) {
        __syncthreads();
        if (tid < 64) {
            float s = 0.f;
#pragma unroll
            for (int ww = 0; ww < 16; ++ww) s += Lred[ww][tid];
            Lvec[(size_t)split * N_TOK + q0 + tid] = s;
        }
    }
}

// ---------------------------------------------------------------------------
// Round-17 FUSED tail: finalize_xr + gemm1(gelu) + gemm2(LayerNorm) in one
// kernel.  Per 16-row block the chain is row-local; XR[16][1536] and
// h[16][768] live in LDS (written directly in the swizzled A-fragment
// layout), deleting 75 MB of XRb/hb global round-trips + 2 launches + all
// per-chunk A-staging barriers.  LDS 74 KB -> 2 blocks/CU at (256,2).
// ---------------------------------------------------------------------------
template <int PLAIN>
__global__ __launch_bounds__(256, 2)
void fused_tail(const float* __restrict__ retrRaw, const float* __restrict__ Lvec,
                const float* __restrict__ cs, const float* __restrict__ gw,
                const float* __restrict__ gb,
                const unsigned short* __restrict__ W12T, const float* __restrict__ fb1,
                const unsigned short* __restrict__ W2T,  const float* __restrict__ fb2,
                const float* __restrict__ gamma, const float* __restrict__ beta,
                float* __restrict__ out)
{
    __shared__ __align__(16) unsigned short XRl[6 * 4096];  // 48 KB: XR[16][1536] swizzled
    __shared__ __align__(16) unsigned short Hl[3 * 4096];   // 24 KB: h[16][768] swizzled
    __shared__ float red[2][4][16];

    const int tid  = threadIdx.x;
    const int w    = tid >> 6;           // wave 0..3
    const int lane = tid & 63;
    const int quad = lane >> 4;
    const int l16  = lane & 15;
    const int row0 = blockIdx.x * 16;
    const int nbase = w * 192;
    const int xsw3 = l16 & 7;
    const int fr   = ((l16 << 2) | quad) << 3;     // fragment-linear lane offset
    const int nb16 = w * 12;                       // first n16-block of this wave

    // ================= stage 1: finalize 16 rows -> XRl =================
#pragma unroll
    for (int it = 0; it < 4; ++it) {
        const int rl = it * 4 + w;                 // local row 0..15
        const int row = row0 + rl;
        const float lv = PLAIN ? (Lvec[row] + Lvec[N_TOK + row]) : Lvec[row];
        const float rli = 1.0f / lv;
        const float* rr  = retrRaw + (size_t)row * DIM;
        const float* rr1 = retrRaw + (size_t)N_TOK * DIM + (size_t)row * DIM;
        const float* cr  = cs + (size_t)row * DIM;

        float4 rv[3], cv[3];
        float d = 0.f;
#pragma unroll
        for (int i = 0; i < 3; ++i) {
            const int c4 = i * 256 + lane * 4;
            float4 r = *(const float4*)&rr[c4];
            if (PLAIN) {
                float4 r1 = *(const float4*)&rr1[c4];
                r.x += r1.x; r.y += r1.y; r.z += r1.z; r.w += r1.w;
            }
            r.x *= rli; r.y *= rli; r.z *= rli; r.w *= rli;
            float4 c = *(const float4*)&cr[c4];
            float4 g1 = *(const float4*)&gw[c4];
            float4 g2 = *(const float4*)&gw[DIM + c4];
            d += c.x * g1.x + c.y * g1.y + c.z * g1.z + c.w * g1.w;
            d += r.x * g2.x + r.y * g2.y + r.z * g2.z + r.w * g2.w;
            rv[i] = r; cv[i] = c;
        }
#pragma unroll
        for (int off = 32; off > 0; off >>= 1) d += __shfl_xor(d, off);
        d += gb[0];
        const float g = 1.0f / (1.0f + __expf(-d));

        const int g8 = lane >> 1;                  // granule within 256-chunk
        const int lo = (lane & 1) * 4;
#pragma unroll
        for (int i = 0; i < 3; ++i) {
            ushort4 xo, ro;
            xo.x = f2bf(cv[i].x + g * rv[i].x); xo.y = f2bf(cv[i].y + g * rv[i].y);
            xo.z = f2bf(cv[i].z + g * rv[i].z); xo.w = f2bf(cv[i].w + g * rv[i].w);
            ro.x = f2bf(rv[i].x); ro.y = f2bf(rv[i].y);
            ro.z = f2bf(rv[i].z); ro.w = f2bf(rv[i].w);
            const int sw = ((g8 ^ (rl & 7)) << 3) + lo;
            *(ushort4*)&XRl[i * 4096 + rl * 256 + sw] = xo;
            *(ushort4*)&XRl[(3 + i) * 4096 + rl * 256 + sw] = ro;
        }
    }
    __syncthreads();

    // ================= stage 2: gemm1 (XRl @ W12T + b1 -> gelu -> Hl) =====
    f32x4 acc[12];
#pragma unroll
    for (int nt = 0; nt < 12; ++nt) acc[nt] = (f32x4){0.f, 0.f, 0.f, 0.f};

    bf16x8 b[12];
#pragma unroll
    for (int nt = 0; nt < 12; ++nt)
        b[nt] = *(const bf16x8*)&W12T[(size_t)(nb16 + nt) * 48 * 512 + fr];

#pragma unroll
    for (int ch = 0; ch < 6; ++ch) {
#pragma unroll
        for (int ks = 0; ks < 8; ++ks) {
            bf16x8 af = *(const bf16x8*)&XRl[ch * 4096 + l16 * 256 + ((((ks << 2) + quad) ^ xsw3) << 3)];
            int kn = ch * 8 + ks + 1;
            if (kn >= 48) kn = 0;                  // dummy wrap
#pragma unroll
            for (int nt = 0; nt < 12; ++nt) {
                acc[nt] = __builtin_amdgcn_mfma_f32_16x16x32_bf16(af, b[nt], acc[nt], 0, 0, 0);
                b[nt] = *(const bf16x8*)&W12T[((size_t)(nb16 + nt) * 48 + kn) * 512 + fr];
            }
        }
    }

    {
        float bv[12];
#pragma unroll
        for (int nt = 0; nt < 12; ++nt) bv[nt] = fb1[nbase + nt * 16 + l16];
#pragma unroll
        for (int nt = 0; nt < 12; ++nt) {
            const int col = nbase + nt * 16 + l16;
            const int cch = col >> 8;
            const int g8  = (col >> 3) & 31;
#pragma unroll
            for (int r = 0; r < 4; ++r) {
                const int rowl = quad * 4 + r;
                float v = acc[nt][r] + bv[nt];
                v = 0.5f * v * (1.0f + erff(v * 0.7071067811865476f));
                Hl[cch * 4096 + rowl * 256 + ((g8 ^ (rowl & 7)) << 3) + (l16 & 7)] = f2bf(v);
            }
        }
    }

    // prefetch gemm2 B while Hl writes drain
    bf16x8 b2[12];
#pragma unroll
    for (int nt = 0; nt < 12; ++nt)
        b2[nt] = *(const bf16x8*)&W2T[(size_t)(nb16 + nt) * 24 * 512 + fr];

    __syncthreads();

    // ================= stage 3: gemm2 (Hl @ W2T + b2 -> LayerNorm -> out) ==
    f32x4 acc2[12];
#pragma unroll
    for (int nt = 0; nt < 12; ++nt) acc2[nt] = (f32x4){0.f, 0.f, 0.f, 0.f};

#pragma unroll
    for (int ch = 0; ch < 3; ++ch) {
#pragma unroll
        for (int ks = 0; ks < 8; ++ks) {
            bf16x8 af = *(const bf16x8*)&Hl[ch * 4096 + l16 * 256 + ((((ks << 2) + quad) ^ xsw3) << 3)];
            int kn = ch * 8 + ks + 1;
            if (kn >= 24) kn = 0;                  // dummy wrap
#pragma unroll
            for (int nt = 0; nt < 12; ++nt) {
                acc2[nt] = __builtin_amdgcn_mfma_f32_16x16x32_bf16(af, b2[nt], acc2[nt], 0, 0, 0);
                b2[nt] = *(const bf16x8*)&W2T[((size_t)(nb16 + nt) * 24 + kn) * 512 + fr];
            }
        }
    }

    {
        float bv[12];
#pragma unroll
        for (int nt = 0; nt < 12; ++nt) bv[nt] = fb2[nbase + nt * 16 + l16];

        float v[12][4];
        float s1[4] = {0.f, 0.f, 0.f, 0.f}, s2[4] = {0.f, 0.f, 0.f, 0.f};
#pragma unroll
        for (int nt = 0; nt < 12; ++nt)
#pragma unroll
            for (int r = 0; r < 4; ++r) {
                float t = acc2[nt][r] + bv[nt];
                v[nt][r] = t;
                s1[r] += t;
                s2[r] += t * t;
            }
#pragma unroll
        for (int r = 0; r < 4; ++r) {
#pragma unroll
            for (int off = 1; off < 16; off <<= 1) {
                s1[r] += __shfl_xor(s1[r], off);
                s2[r] += __shfl_xor(s2[r], off);
            }
            if (l16 == 0) {
                red[0][w][quad * 4 + r] = s1[r];
                red[1][w][quad * 4 + r] = s2[r];
            }
        }
        __syncthreads();
#pragma unroll
        for (int r = 0; r < 4; ++r) {
            const int rl16 = quad * 4 + r;
            const float t1 = red[0][0][rl16] + red[0][1][rl16] + red[0][2][rl16] + red[0][3][rl16];
            const float t2 = red[1][0][rl16] + red[1][1][rl16] + red[1][2][rl16] + red[1][3][rl16];
            const float mu  = t1 * (1.0f / 768.0f);
            const float var = fmaxf(t2 * (1.0f / 768.0f) - mu * mu, 0.f);
            const float rs  = rsqrtf(var + 1e-5f);
            const int row = row0 + rl16;
#pragma unroll
            for (int nt = 0; nt < 12; ++nt) {
                const int col = nbase + nt * 16 + l16;
                out[(size_t)row * DIM + col] = (v[nt][r] - mu) * rs * gamma[col] + beta[col];
            }
        }
    }
}

// ---------------------------------------------------------------------------
extern "C" void kernel_launch(void* const* d_in, const int* in_sizes, int n_in,
                              void* d_out, int out_size, void* d_ws, size_t ws_size,
                              hipStream_t stream)
{
    const float* cs  = (const float*)d_in[0];
    const float* mem = (const float*)d_in[1];
    const float* gw  = (const float*)d_in[2];
    const float* gb  = (const float*)d_in[3];
    const float* fw1 = (const float*)d_in[4];
    const float* fb1 = (const float*)d_in[5];
    const float* fw2 = (const float*)d_in[6];
    const float* fb2 = (const float*)d_in[7];
    const float* gam = (const float*)d_in[8];
    const float* bet = (const float*)d_in[9];
    float* out = (float*)d_out;

    char* ws = (char*)d_ws;
    // Layout A (atomic fallback, ~72.8 MB) / Layout B (plain, ~98 MB):
    const size_t PLAIN_WS = 97976320;
    const bool plain = (ws_size >= PLAIN_WS);

    unsigned short* memF = (unsigned short*)ws;                 // 15,728,640
    unsigned short* memS = (unsigned short*)(ws + 15728640);    // 15,728,640
    unsigned short* qH   = (unsigned short*)(ws + 31457280);    // 12,582,912
    float*          retr = (float*)(ws + 44040192);             // A: 25,165,824 / B: 50,331,648
    float*          Lvec;
    unsigned short* w12T;
    unsigned short* w2T;
    if (plain) {
        Lvec = (float*)(ws + 94371840);            // 65,536 (2 splits)
        w12T = (unsigned short*)(ws + 94437376);   // 2,359,296
        w2T  = (unsigned short*)(ws + 96796672);   // 1,179,648 -> end 97,976,320
    } else {
        Lvec = (float*)(ws + 69206016);            // 32,768
        w12T = (unsigned short*)(ws + 69238784);   // 2,359,296
        w2T  = (unsigned short*)(ws + 71598080);   // 1,179,648 -> end 72,777,728
    }

    if (!plain)
        hipMemsetAsync(retr, 0, 25165824 + 32768, stream);      // atomic path needs zeroed accum

    cvt_memF<<<MEMP / 16, 256, 0, stream>>>(mem, memF);
    cvt_qH<<<(N_TOK * DIM) / (256 * 4), 256, 0, stream>>>(cs, qH);
    cvt_memS<<<dim3(MEMP / 32, DIM / 64), 256, 0, stream>>>(mem, memS);
    prep_w12T<<<dim3(48, 24), 256, 0, stream>>>(fw1, w12T);
    prep_w2T<<<dim3(24, 24), 256, 0, stream>>>(fw2, w2T);

    if (plain) {
        attn_mfma<1><<<dim3(N_TOK / TQ, NSPLIT), 1024, 0, stream>>>(qH, memF, memS, retr, Lvec);
        fused_tail<1><<<N_TOK / 16, 256, 0, stream>>>(retr, Lvec, cs, gw, gb,
                                                      w12T, fb1, w2T, fb2, gam, bet, out);
    } else {
        attn_mfma<0><<<dim3(N_TOK / TQ, NSPLIT), 1024, 0, stream>>>(qH, memF, memS, retr, Lvec);
        fused_tail<0><<<N_TOK / 16, 256, 0, stream>>>(retr, Lvec, cs, gw, gb,
                                                      w12T, fb1, w2T, fb2, gam, bet, out);
    }
}

// Round 11
// 822.470 us; speedup vs baseline: 1.3486x; 1.0198x over previous
//
#include <hip/hip_runtime.h>
#include <math.h>

#define N_TOK 8192
#define DIM   768
#define MEMN  10000
#define MEMP  10240            // padded to 40*256
#define TQ    64
#define TM    256
#define NSPLIT 2
#define TILES_PER_SPLIT 20

constexpr float SCALE = 0.036084391824351615f;  // 1/sqrt(768)

typedef short bf16x8 __attribute__((ext_vector_type(8)));
typedef float f32x4  __attribute__((ext_vector_type(4)));

__device__ __forceinline__ unsigned short f2bf(float f) {
    unsigned u = __float_as_uint(f);
    unsigned r = (u + 0x7fffu + ((u >> 16) & 1u)) >> 16;   // RTN-even
    return (unsigned short)r;
}

// ---------------------------------------------------------------------------
// prep_all: ONE launch for all operand conversions (round-18; was 4 kernels).
//   blocks [0,640):        memF  fragment-linear bf16 of mem (phase-1 B)
//   blocks [640,4480):     memS  fragment-linear transposed mem (phase-2 B)
//   blocks [4480,5632):    w12T  fragment-linear fused-W1 (gemm1 B)
//   blocks [5632,6208):    w2T   fragment-linear W2 (gemm2 B)
// Branches are block-uniform. Shared T[32][65] covers both transpose tiles.
// ---------------------------------------------------------------------------
__global__ __launch_bounds__(256)
void prep_all(const float* __restrict__ mem, const float* __restrict__ w1,
              const float* __restrict__ w2,
              unsigned short* __restrict__ memF, unsigned short* __restrict__ memS,
              unsigned short* __restrict__ w12T, unsigned short* __restrict__ w2T)
{
    __shared__ float T[32][65];
    const int bid = blockIdx.x;

    if (bid < 640) {
        // ---- memF: slot(mb,kc,l16,quad,j) = mem[mb*16+l16][kc*32+quad*8+j]
        const int mb = bid;
        const bool zero = (mb >= MEMN / 16);
#pragma unroll
        for (int it = 0; it < 6; ++it) {
            const int s   = it * 256 + threadIdx.x;      // 0..1535
            const int kc  = s >> 6;
            const int r   = s & 63;
            const int l16 = r >> 2, q = r & 3;
            unsigned short o[8];
            if (!zero) {
                const float* src = &mem[(size_t)(mb * 16 + l16) * DIM + kc * 32 + q * 8];
                float4 v0 = *(const float4*)src;
                float4 v1 = *(const float4*)(src + 4);
                o[0] = f2bf(v0.x); o[1] = f2bf(v0.y); o[2] = f2bf(v0.z); o[3] = f2bf(v0.w);
                o[4] = f2bf(v1.x); o[5] = f2bf(v1.y); o[6] = f2bf(v1.z); o[7] = f2bf(v1.w);
            } else {
#pragma unroll
                for (int j = 0; j < 8; ++j) o[j] = 0;
            }
            *(uint4*)&memF[((size_t)mb * 24 + kc) * 512 + r * 8] = *(const uint4*)o;
        }
    } else if (bid < 4480) {
        // ---- memS: slot(db,mc,l16,quad,j) = mem[mc*32+quad*8+j][db*16+l16]
        const int rr = bid - 640;
        const int mc = rr % 320;
        const int d0 = (rr / 320) * 64;
        const int tx = threadIdx.x & 63;
        const int ty = threadIdx.x >> 6;
#pragma unroll
        for (int i = 0; i < 8; ++i) {
            const int row = ty + 4 * i;                  // 0..31
            const int m   = mc * 32 + row;
            T[row][tx] = (m < MEMN) ? mem[(size_t)m * DIM + d0 + tx] : 0.f;
        }
        __syncthreads();
        const int dbl = threadIdx.x >> 6;
        const int r   = threadIdx.x & 63;
        const int l16 = r >> 2, q = r & 3;
        unsigned short o[8];
#pragma unroll
        for (int j = 0; j < 8; ++j) o[j] = f2bf(T[q * 8 + j][dbl * 16 + l16]);
        *(uint4*)&memS[((size_t)(d0 / 16 + dbl) * 320 + mc) * 512 + r * 8] = *(const uint4*)o;
    } else if (bid < 5632) {
        // ---- w12T: 48 n16-blocks x 48 kc, W[n][k]=w1[768+k][n]+ (k<768? w1[k][n]:0)
        const int rr = bid - 4480;
        const int kb = (rr % 48) * 32;
        const int nb = (rr / 48) * 32;
        const int tx = threadIdx.x & 31, ty = threadIdx.x >> 5;
#pragma unroll
        for (int i = 0; i < 4; ++i) {
            int k = kb + ty + 8 * i;
            float v = w1[(size_t)(768 + k) * DIM + nb + tx];
            if (kb < 768) v += w1[(size_t)k * DIM + nb + tx];
            T[ty + 8 * i][tx] = v;              // T[k_local][n_local]
        }
        __syncthreads();
        if (threadIdx.x < 128) {
            const int sub = threadIdx.x >> 6;
            const int r   = threadIdx.x & 63;
            const int l16 = r >> 2, q = r & 3;
            unsigned short o[8];
#pragma unroll
            for (int j = 0; j < 8; ++j) o[j] = f2bf(T[q * 8 + j][sub * 16 + l16]);
            const int n16 = (nb >> 4) + sub;
            const int kc  = kb >> 5;
            *(uint4*)&w12T[((size_t)n16 * 48 + kc) * 512 + r * 8] = *(const uint4*)o;
        }
    } else {
        // ---- w2T: 48 n16-blocks x 24 kc, W[n][k]=w2[k][n]
        const int rr = bid - 5632;
        const int kb = (rr % 24) * 32;
        const int nb = (rr / 24) * 32;
        const int tx = threadIdx.x & 31, ty = threadIdx.x >> 5;
#pragma unroll
        for (int i = 0; i < 4; ++i)
            T[ty + 8 * i][tx] = w2[(size_t)(kb + ty + 8 * i) * DIM + nb + tx];
        __syncthreads();
        if (threadIdx.x < 128) {
            const int sub = threadIdx.x >> 6;
            const int r   = threadIdx.x & 63;
            const int l16 = r >> 2, q = r & 3;
            unsigned short o[8];
#pragma unroll
            for (int j = 0; j < 8; ++j) o[j] = f2bf(T[q * 8 + j][sub * 16 + l16]);
            const int n16 = (nb >> 4) + sub;
            const int kc  = kb >> 5;
            *(uint4*)&w2T[((size_t)n16 * 24 + kc) * 512 + r * 8] = *(const uint4*)o;
        }
    }
}

// ---------------------------------------------------------------------------
// Fused MFMA attention. Round-15 main loop (VERIFIED 599-609 us) UNCHANGED.
// Round-18: Q staged directly from fp32 cs (cvt_qH kernel + qH buffer
// deleted; conversion happens in the staging prologue).
// ---------------------------------------------------------------------------
template <int PLAIN>
__global__ __launch_bounds__(1024, 4)
void attn_mfma(const float* __restrict__ cs, const unsigned short* __restrict__ memF,
               const unsigned short* __restrict__ memS,
               float* __restrict__ retrRaw, float* __restrict__ Lvec)
{
    __shared__ __align__(16) unsigned short Qs[64 * 768];   // 96 KB, xor-swizzled
    __shared__ __align__(16) unsigned short Ps[64 * 256];   // 32 KB, xor-swizzled
    __shared__ float Lred[16][64];                          // 4 KB, L block-reduce

    const int tid    = threadIdx.x;
    const int w      = tid >> 6;         // wave 0..15
    const int lane   = tid & 63;
    const int quad   = lane >> 4;        // 0..3
    const int l16    = lane & 15;
    const int fr     = ((l16 << 2) | quad) << 3;   // fragment-linear lane offset (ushorts)

    const int split = blockIdx.y;
    const int q0    = blockIdx.x * TQ;   // 0..8128 step 64

    const int dbase  = w * 48;           // phase-2 d-strip per wave (3 x 16)
    const int mstrip = w * 16;           // phase-1 m-strip per wave (1 x 16)

    // ---- stage Q tile (64 rows) from fp32, convert to bf16, swizzled ----
    {
        const int qr  = tid >> 4;            // 0..63
        const int db0 = tid & 15;
        const float* src = cs + (size_t)(q0 + qr) * DIM;
        const int sw = qr & 7;
#pragma unroll
        for (int i = 0; i < 6; ++i) {
            int db = db0 + i * 16;           // 0..95 (blocks of 8 bf16)
            float4 v0 = *(const float4*)&src[db * 8];
            float4 v1 = *(const float4*)&src[db * 8 + 4];
            unsigned short o[8];
            o[0] = f2bf(v0.x); o[1] = f2bf(v0.y); o[2] = f2bf(v0.z); o[3] = f2bf(v0.w);
            o[4] = f2bf(v1.x); o[5] = f2bf(v1.y); o[6] = f2bf(v1.z); o[7] = f2bf(v1.w);
            *(uint4*)&Qs[qr * 768 + ((db ^ sw) << 3)] = *(const uint4*)o;
        }
    }
    __syncthreads();

    f32x4 oacc[4][3];
#pragma unroll
    for (int a = 0; a < 4; ++a)
#pragma unroll
        for (int b = 0; b < 3; ++b) oacc[a][b] = (f32x4){0.f, 0.f, 0.f, 0.f};
    float lsum[4][4];
#pragma unroll
    for (int a = 0; a < 4; ++a)
#pragma unroll
        for (int r = 0; r < 4; ++r) lsum[a][r] = 0.f;

    const int xsw = l16 & 7;

    for (int st = 0; st < TILES_PER_SPLIT; ++st) {
        const int m0  = (split * TILES_PER_SPLIT + st) * TM;
        const int mc0 = m0 >> 5;

        // ---- phase 1: S[64 x 256]; wave w covers m-strip mstrip..+16 ----
        f32x4 sacc[4];
#pragma unroll
        for (int a = 0; a < 4; ++a) sacc[a] = (f32x4){0.f, 0.f, 0.f, 0.f};

        const unsigned short* fb = memF + ((size_t)(m0 >> 4) + w) * 12288 + fr;

        bf16x8 pb[2];
        pb[0] = *(const bf16x8*)(fb);
        pb[1] = *(const bf16x8*)(fb + 512);

#pragma unroll
        for (int ks = 0; ks < 24; ++ks) {
            const int xq = (((ks << 2) + quad) ^ xsw) << 3;
            bf16x8 a0 = *(const bf16x8*)&Qs[l16 * 768 + xq];
            bf16x8 a1 = *(const bf16x8*)&Qs[(16 + l16) * 768 + xq];
            bf16x8 a2 = *(const bf16x8*)&Qs[(32 + l16) * 768 + xq];
            bf16x8 a3 = *(const bf16x8*)&Qs[(48 + l16) * 768 + xq];
            bf16x8 b = pb[ks & 1];
            sacc[0] = __builtin_amdgcn_mfma_f32_16x16x32_bf16(a0, b, sacc[0], 0, 0, 0);
            sacc[1] = __builtin_amdgcn_mfma_f32_16x16x32_bf16(a1, b, sacc[1], 0, 0, 0);
            sacc[2] = __builtin_amdgcn_mfma_f32_16x16x32_bf16(a2, b, sacc[2], 0, 0, 0);
            sacc[3] = __builtin_amdgcn_mfma_f32_16x16x32_bf16(a3, b, sacc[3], 0, 0, 0);
            if (ks < 22) pb[ks & 1] = *(const bf16x8*)(fb + (ks + 2) * 512);
        }

        __syncthreads();   // barrier A

        // ---- exp + P->LDS (bf16, swizzled) + row-sum accumulation ----
        {
            const int mloc = mstrip + l16;               // 0..255
            const bool ok  = (m0 + mloc) < MEMN;
#pragma unroll
            for (int qt = 0; qt < 4; ++qt)
#pragma unroll
                for (int r = 0; r < 4; ++r) {
                    float p = ok ? __expf(sacc[qt][r] * SCALE) : 0.f;
                    const int q = qt * 16 + quad * 4 + r;     // 0..63
                    lsum[qt][r] += p;
                    Ps[q * 256 + (((mloc >> 3) ^ (q & 7)) << 3) + (mloc & 7)] = f2bf(p);
                }
        }

        __syncthreads();   // barrier B

        // ---- phase 2: O += P * Mem; depth-2 register prefetch of B-frags ----
        const unsigned short* msp = memS + ((size_t)(3 * w) * 320 + mc0) * 512 + fr;
        bf16x8 cb[2][3];
#pragma unroll
        for (int nt = 0; nt < 3; ++nt) {
            cb[0][nt] = *(const bf16x8*)(msp + (size_t)nt * 163840);
            cb[1][nt] = *(const bf16x8*)(msp + (size_t)nt * 163840 + 512);
        }

#pragma unroll
        for (int ks = 0; ks < 8; ++ks) {
            const int xp = (((ks << 2) + quad) ^ xsw) << 3;
            bf16x8 pa0 = *(const bf16x8*)&Ps[l16 * 256 + xp];
            bf16x8 pa1 = *(const bf16x8*)&Ps[(16 + l16) * 256 + xp];
            bf16x8 pa2 = *(const bf16x8*)&Ps[(32 + l16) * 256 + xp];
            bf16x8 pa3 = *(const bf16x8*)&Ps[(48 + l16) * 256 + xp];
            const bool dopf = (ks < 6);
#pragma unroll
            for (int nt = 0; nt < 3; ++nt) {
                oacc[0][nt] = __builtin_amdgcn_mfma_f32_16x16x32_bf16(pa0, cb[ks & 1][nt], oacc[0][nt], 0, 0, 0);
                oacc[1][nt] = __builtin_amdgcn_mfma_f32_16x16x32_bf16(pa1, cb[ks & 1][nt], oacc[1][nt], 0, 0, 0);
                oacc[2][nt] = __builtin_amdgcn_mfma_f32_16x16x32_bf16(pa2, cb[ks & 1][nt], oacc[2][nt], 0, 0, 0);
                oacc[3][nt] = __builtin_amdgcn_mfma_f32_16x16x32_bf16(pa3, cb[ks & 1][nt], oacc[3][nt], 0, 0, 0);
                if (dopf) cb[ks & 1][nt] = *(const bf16x8*)(msp + (size_t)nt * 163840 + (ks + 2) * 512);
            }
        }
    }

    // ---- epilogue: combine O and L across splits ----
    float* ob = retrRaw + (PLAIN ? (size_t)split * ((size_t)N_TOK * DIM) : (size_t)0);
#pragma unroll
    for (int qt = 0; qt < 4; ++qt)
#pragma unroll
        for (int nt = 0; nt < 3; ++nt)
#pragma unroll
            for (int r = 0; r < 4; ++r) {
                const size_t idx = (size_t)(q0 + qt * 16 + quad * 4 + r) * DIM + dbase + nt * 16 + l16;
                if (PLAIN)
                    ob[idx] = oacc[qt][nt][r];
                else
                    __hip_atomic_fetch_add(&ob[idx], oacc[qt][nt][r],
                                           __ATOMIC_RELAXED, __HIP_MEMORY_SCOPE_AGENT);
            }

#pragma unroll
    for (int qt = 0; qt < 4; ++qt)
#pragma unroll
        for (int r = 0; r < 4; ++r) {
            float v = lsum[qt][r];
#pragma unroll
            for (int off = 1; off < 16; off <<= 1) v += __shfl_xor(v, off);
            if (l16 == 0) {
                if (PLAIN)
                    Lred[w][qt * 16 + quad * 4 + r] = v;
                else
                    __hip_atomic_fetch_add(&Lvec[q0 + qt * 16 + quad * 4 + r], v,
                                           __ATOMIC_RELAXED, __HIP_MEMORY_SCOPE_AGENT);
            }
        }
    if (PLAIN) {
        __syncthreads();
        if (tid < 64) {
            float s = 0.f;
#pragma unroll
            for (int ww = 0; ww < 16; ++ww) s += Lred[ww][tid];
            Lvec[(size_t)split * N_TOK + q0 + tid] = s;
        }
    }
}

// ---------------------------------------------------------------------------
// Fused tail (round-17, VERIFIED): finalize_xr + gemm1(gelu) + gemm2(LN).
// ---------------------------------------------------------------------------
template <int PLAIN>
__global__ __launch_bounds__(256, 2)
void fused_tail(const float* __restrict__ retrRaw, const float* __restrict__ Lvec,
                const float* __restrict__ cs, const float* __restrict__ gw,
                const float* __restrict__ gb,
                const unsigned short* __restrict__ W12T, const float* __restrict__ fb1,
                const unsigned short* __restrict__ W2T,  const float* __restrict__ fb2,
                const float* __restrict__ gamma, const float* __restrict__ beta,
                float* __restrict__ out)
{
    __shared__ __align__(16) unsigned short XRl[6 * 4096];  // 48 KB: XR[16][1536] swizzled
    __shared__ __align__(16) unsigned short Hl[3 * 4096];   // 24 KB: h[16][768] swizzled
    __shared__ float red[2][4][16];

    const int tid  = threadIdx.x;
    const int w    = tid >> 6;           // wave 0..3
    const int lane = tid & 63;
    const int quad = lane >> 4;
    const int l16  = lane & 15;
    const int row0 = blockIdx.x * 16;
    const int nbase = w * 192;
    const int xsw3 = l16 & 7;
    const int fr   = ((l16 << 2) | quad) << 3;     // fragment-linear lane offset
    const int nb16 = w * 12;                       // first n16-block of this wave

    // ================= stage 1: finalize 16 rows -> XRl =================
#pragma unroll
    for (int it = 0; it < 4; ++it) {
        const int rl = it * 4 + w;                 // local row 0..15
        const int row = row0 + rl;
        const float lv = PLAIN ? (Lvec[row] + Lvec[N_TOK + row]) : Lvec[row];
        const float rli = 1.0f / lv;
        const float* rr  = retrRaw + (size_t)row * DIM;
        const float* rr1 = retrRaw + (size_t)N_TOK * DIM + (size_t)row * DIM;
        const float* cr  = cs + (size_t)row * DIM;

        float4 rv[3], cv[3];
        float d = 0.f;
#pragma unroll
        for (int i = 0; i < 3; ++i) {
            const int c4 = i * 256 + lane * 4;
            float4 r = *(const float4*)&rr[c4];
            if (PLAIN) {
                float4 r1 = *(const float4*)&rr1[c4];
                r.x += r1.x; r.y += r1.y; r.z += r1.z; r.w += r1.w;
            }
            r.x *= rli; r.y *= rli; r.z *= rli; r.w *= rli;
            float4 c = *(const float4*)&cr[c4];
            float4 g1 = *(const float4*)&gw[c4];
            float4 g2 = *(const float4*)&gw[DIM + c4];
            d += c.x * g1.x + c.y * g1.y + c.z * g1.z + c.w * g1.w;
            d += r.x * g2.x + r.y * g2.y + r.z * g2.z + r.w * g2.w;
            rv[i] = r; cv[i] = c;
        }
#pragma unroll
        for (int off = 32; off > 0; off >>= 1) d += __shfl_xor(d, off);
        d += gb[0];
        const float g = 1.0f / (1.0f + __expf(-d));

        const int g8 = lane >> 1;                  // granule within 256-chunk
        const int lo = (lane & 1) * 4;
#pragma unroll
        for (int i = 0; i < 3; ++i) {
            ushort4 xo, ro;
            xo.x = f2bf(cv[i].x + g * rv[i].x); xo.y = f2bf(cv[i].y + g * rv[i].y);
            xo.z = f2bf(cv[i].z + g * rv[i].z); xo.w = f2bf(cv[i].w + g * rv[i].w);
            ro.x = f2bf(rv[i].x); ro.y = f2bf(rv[i].y);
            ro.z = f2bf(rv[i].z); ro.w = f2bf(rv[i].w);
            const int sw = ((g8 ^ (rl & 7)) << 3) + lo;
            *(ushort4*)&XRl[i * 4096 + rl * 256 + sw] = xo;
            *(ushort4*)&XRl[(3 + i) * 4096 + rl * 256 + sw] = ro;
        }
    }
    __syncthreads();

    // ================= stage 2: gemm1 (XRl @ W12T + b1 -> gelu -> Hl) =====
    f32x4 acc[12];
#pragma unroll
    for (int nt = 0; nt < 12; ++nt) acc[nt] = (f32x4){0.f, 0.f, 0.f, 0.f};

    bf16x8 b[12];
#pragma unroll
    for (int nt = 0; nt < 12; ++nt)
        b[nt] = *(const bf16x8*)&W12T[(size_t)(nb16 + nt) * 48 * 512 + fr];

#pragma unroll
    for (int ch = 0; ch < 6; ++ch) {
#pragma unroll
        for (int ks = 0; ks < 8; ++ks) {
            bf16x8 af = *(const bf16x8*)&XRl[ch * 4096 + l16 * 256 + ((((ks << 2) + quad) ^ xsw3) << 3)];
            int kn = ch * 8 + ks + 1;
            if (kn >= 48) kn = 0;                  // dummy wrap
#pragma unroll
            for (int nt = 0; nt < 12; ++nt) {
                acc[nt] = __builtin_amdgcn_mfma_f32_16x16x32_bf16(af, b[nt], acc[nt], 0, 0, 0);
                b[nt] = *(const bf16x8*)&W12T[((size_t)(nb16 + nt) * 48 + kn) * 512 + fr];
            }
        }
    }

    {
        float bv[12];
#pragma unroll
        for (int nt = 0; nt < 12; ++nt) bv[nt] = fb1[nbase + nt * 16 + l16];
#pragma unroll
        for (int nt = 0; nt < 12; ++nt) {
            const int col = nbase + nt * 16 + l16;
            const int cch = col >> 8;
            const int g8  = (col >> 3) & 31;
#pragma unroll
            for (int r = 0; r < 4; ++r) {
                const int rowl = quad * 4 + r;
                float v = acc[nt][r] + bv[nt];
                v = 0.5f * v * (1.0f + erff(v * 0.7071067811865476f));
                Hl[cch * 4096 + rowl * 256 + ((g8 ^ (rowl & 7)) << 3) + (l16 & 7)] = f2bf(v);
            }
        }
    }

    // prefetch gemm2 B while Hl writes drain
    bf16x8 b2[12];
#pragma unroll
    for (int nt = 0; nt < 12; ++nt)
        b2[nt] = *(const bf16x8*)&W2T[(size_t)(nb16 + nt) * 24 * 512 + fr];

    __syncthreads();

    // ================= stage 3: gemm2 (Hl @ W2T + b2 -> LayerNorm -> out) ==
    f32x4 acc2[12];
#pragma unroll
    for (int nt = 0; nt < 12; ++nt) acc2[nt] = (f32x4){0.f, 0.f, 0.f, 0.f};

#pragma unroll
    for (int ch = 0; ch < 3; ++ch) {
#pragma unroll
        for (int ks = 0; ks < 8; ++ks) {
            bf16x8 af = *(const bf16x8*)&Hl[ch * 4096 + l16 * 256 + ((((ks << 2) + quad) ^ xsw3) << 3)];
            int kn = ch * 8 + ks + 1;
            if (kn >= 24) kn = 0;                  // dummy wrap
#pragma unroll
            for (int nt = 0; nt < 12; ++nt) {
                acc2[nt] = __builtin_amdgcn_mfma_f32_16x16x32_bf16(af, b2[nt], acc2[nt], 0, 0, 0);
                b2[nt] = *(const bf16x8*)&W2T[((size_t)(nb16 + nt) * 24 + kn) * 512 + fr];
            }
        }
    }

    {
        float bv[12];
#pragma unroll
        for (int nt = 0; nt < 12; ++nt) bv[nt] = fb2[nbase + nt * 16 + l16];

        float v[12][4];
        float s1[4] = {0.f, 0.f, 0.f, 0.f}, s2[4] = {0.f, 0.f, 0.f, 0.f};
#pragma unroll
        for (int nt = 0; nt < 12; ++nt)
#pragma unroll
            for (int r = 0; r < 4; ++r) {
                float t = acc2[nt][r] + bv[nt];
                v[nt][r] = t;
                s1[r] += t;
                s2[r] += t * t;
            }
#pragma unroll
        for (int r = 0; r < 4; ++r) {
#pragma unroll
            for (int off = 1; off < 16; off <<= 1) {
                s1[r] += __shfl_xor(s1[r], off);
                s2[r] += __shfl_xor(s2[r], off);
            }
            if (l16 == 0) {
                red[0][w][quad * 4 + r] = s1[r];
                red[1][w][quad * 4 + r] = s2[r];
            }
        }
        __syncthreads();
#pragma unroll
        for (int r = 0; r < 4; ++r) {
            const int rl16 = quad * 4 + r;
            const float t1 = red[0][0][rl16] + red[0][1][rl16] + red[0][2][rl16] + red[0][3][rl16];
            const float t2 = red[1][0][rl16] + red[1][1][rl16] + red[1][2][rl16] + red[1][3][rl16];
            const float mu  = t1 * (1.0f / 768.0f);
            const float var = fmaxf(t2 * (1.0f / 768.0f) - mu * mu, 0.f);
            const float rs  = rsqrtf(var + 1e-5f);
            const int row = row0 + rl16;
#pragma unroll
            for (int nt = 0; nt < 12; ++nt) {
                const int col = nbase + nt * 16 + l16;
                out[(size_t)row * DIM + col] = (v[nt][r] - mu) * rs * gamma[col] + beta[col];
            }
        }
    }
}

// ---------------------------------------------------------------------------
extern "C" void kernel_launch(void* const* d_in, const int* in_sizes, int n_in,
                              void* d_out, int out_size, void* d_ws, size_t ws_size,
                              hipStream_t stream)
{
    const float* cs  = (const float*)d_in[0];
    const float* mem = (const float*)d_in[1];
    const float* gw  = (const float*)d_in[2];
    const float* gb  = (const float*)d_in[3];
    const float* fw1 = (const float*)d_in[4];
    const float* fb1 = (const float*)d_in[5];
    const float* fw2 = (const float*)d_in[6];
    const float* fb2 = (const float*)d_in[7];
    const float* gam = (const float*)d_in[8];
    const float* bet = (const float*)d_in[9];
    float* out = (float*)d_out;

    char* ws = (char*)d_ws;
    // Layout A (atomic fallback, ~72.8 MB) / Layout B (plain, ~98 MB):
    const size_t PLAIN_WS = 97976320;
    const bool plain = (ws_size >= PLAIN_WS);

    unsigned short* memF = (unsigned short*)ws;                 // 15,728,640
    unsigned short* memS = (unsigned short*)(ws + 15728640);    // 15,728,640
    // (qH region ws+31457280..44040192 now unused; kept for layout stability)
    float*          retr = (float*)(ws + 44040192);             // A: 25,165,824 / B: 50,331,648
    float*          Lvec;
    unsigned short* w12T;
    unsigned short* w2T;
    if (plain) {
        Lvec = (float*)(ws + 94371840);            // 65,536 (2 splits)
        w12T = (unsigned short*)(ws + 94437376);   // 2,359,296
        w2T  = (unsigned short*)(ws + 96796672);   // 1,179,648 -> end 97,976,320
    } else {
        Lvec = (float*)(ws + 69206016);            // 32,768
        w12T = (unsigned short*)(ws + 69238784);   // 2,359,296
        w2T  = (unsigned short*)(ws + 71598080);   // 1,179,648 -> end 72,777,728
    }

    if (!plain)
        hipMemsetAsync(retr, 0, 25165824 + 32768, stream);      // atomic path needs zeroed accum

    prep_all<<<6208, 256, 0, stream>>>(mem, fw1, fw2, memF, memS, w12T, w2T);

    if (plain) {
        attn_mfma<1><<<dim3(N_TOK / TQ, NSPLIT), 1024, 0, stream>>>(cs, memF, memS, retr, Lvec);
        fused_tail<1><<<N_TOK / 16, 256, 0, stream>>>(retr, Lvec, cs, gw, gb,
                                                      w12T, fb1, w2T, fb2, gam, bet, out);
    } else {
        attn_mfma<0><<<dim3(N_TOK / TQ, NSPLIT), 1024, 0, stream>>>(cs, memF, memS, retr, Lvec);
        fused_tail<0><<<N_TOK / 16, 256, 0, stream>>>(retr, Lvec, cs, gw, gb,
                                                      w12T, fb1, w2T, fb2, gam, bet, out);
    }
}